// Round 1
// baseline (26057.828 us; speedup 1.0000x reference)
//
#include <hip/hip_runtime.h>
#include <cstdint>

#define N_NODES 100000
#define N_EDGES 1600000
#define H 8
#define D 16
#define HD 128
#define G_GRAPHS 128
#define OUT_DIM 64
#define EPS 1e-3f
#define NEG 0.2f

__device__ __forceinline__ int f2ord(float f) {
    int i = __float_as_int(f);
    return i >= 0 ? i : (i ^ 0x7fffffff);
}
__device__ __forceinline__ float ord2f(int i) {
    return __int_as_float(i >= 0 ? i : (i ^ 0x7fffffff));
}

// ---- zero / init per-layer scratch --------------------------------------
__global__ void init_layer(float* __restrict__ gat, float* __restrict__ denom,
                           int* __restrict__ emax, float* __restrict__ sums,
                           float* __restrict__ pooled, int zero_pooled) {
    int tid = blockIdx.x * blockDim.x + threadIdx.x;
    int stride = gridDim.x * blockDim.x;
    for (int i = tid; i < N_NODES * HD; i += stride) gat[i] = 0.f;
    for (int i = tid; i < N_NODES * H; i += stride) { denom[i] = 0.f; emax[i] = (int)0x80000000; }
    if (tid < 256) sums[tid] = 0.f;
    if (zero_pooled) {
        for (int i = tid; i < G_GRAPHS * HD; i += stride) pooled[i] = 0.f;
    }
}

// ---- feat = X @ W  (X:[nrows,128], W:[128,128]) -------------------------
__global__ __launch_bounds__(256) void gemm128(const float* __restrict__ X,
                                               const float* __restrict__ W,
                                               float* __restrict__ Y, int nrows) {
    __shared__ float Ws[HD * HD];
    __shared__ float xs[8][HD];
    for (int i = threadIdx.x; i < HD * HD; i += 256) Ws[i] = W[i];
    int c4 = (threadIdx.x & 31) * 4;
    int rs = threadIdx.x >> 5;  // 0..7
    int base = blockIdx.x * 64;
    for (int it = 0; it < 8; ++it) {
        int r0 = base + it * 8;
        __syncthreads();
        {
            int lr = r0 + (threadIdx.x >> 5);
            int lc = (threadIdx.x & 31) * 4;
            if (lr < nrows) *(float4*)&xs[threadIdx.x >> 5][lc] = *(const float4*)&X[lr * HD + lc];
        }
        __syncthreads();
        int r = r0 + rs;
        if (r < nrows) {
            float4 acc = {0.f, 0.f, 0.f, 0.f};
#pragma unroll
            for (int k = 0; k < HD; ++k) {
                float xv = xs[rs][k];
                float4 w = *(float4*)&Ws[k * HD + c4];
                acc.x += xv * w.x; acc.y += xv * w.y;
                acc.z += xv * w.z; acc.w += xv * w.w;
            }
            *(float4*)&Y[r * HD + c4] = acc;
        }
    }
}

// ---- el/er: per (node, head) dot of feat with attn vectors --------------
__global__ void compute_elr(const float* __restrict__ feat, const float* __restrict__ al,
                            const float* __restrict__ ar, float* __restrict__ el,
                            float* __restrict__ er) {
    int t = blockIdx.x * blockDim.x + threadIdx.x;
    if (t >= N_NODES * H) return;
    int n = t >> 3, h = t & 7;
    const float4* f = (const float4*)&feat[n * HD + h * D];
    const float4* a = (const float4*)&al[h * D];
    const float4* b = (const float4*)&ar[h * D];
    float sl = 0.f, sr = 0.f;
#pragma unroll
    for (int i = 0; i < 4; ++i) {
        float4 fv = f[i], av = a[i], bv = b[i];
        sl += fv.x * av.x + fv.y * av.y + fv.z * av.z + fv.w * av.w;
        sr += fv.x * bv.x + fv.y * bv.y + fv.z * bv.z + fv.w * bv.w;
    }
    el[t] = sl;
    er[t] = sr;
}

// ---- edge pass 1: segment max of leaky(el[src]+er[dst]) over dst --------
__global__ void edge_max(const int* __restrict__ src, const int* __restrict__ dst,
                         const float* __restrict__ el, const float* __restrict__ er,
                         int* __restrict__ emax) {
    int e = blockIdx.x * blockDim.x + threadIdx.x;
    if (e >= N_EDGES) return;
    int s = src[e], d0 = dst[e];
    const float4* pl = (const float4*)&el[s * H];
    const float4* pr = (const float4*)&er[d0 * H];
    float4 l0 = pl[0], l1 = pl[1], r0 = pr[0], r1 = pr[1];
    float ev[8] = {l0.x + r0.x, l0.y + r0.y, l0.z + r0.z, l0.w + r0.w,
                   l1.x + r1.x, l1.y + r1.y, l1.z + r1.z, l1.w + r1.w};
#pragma unroll
    for (int h = 0; h < 8; ++h) {
        float v = ev[h];
        v = v >= 0.f ? v : NEG * v;
        atomicMax(&emax[d0 * H + h], f2ord(v));
    }
}

// ---- edge pass 2: denom = segment sum of exp(e - emax[dst]) -------------
__global__ void edge_denom(const int* __restrict__ src, const int* __restrict__ dst,
                           const float* __restrict__ el, const float* __restrict__ er,
                           const int* __restrict__ emax, float* __restrict__ denom) {
    int e = blockIdx.x * blockDim.x + threadIdx.x;
    if (e >= N_EDGES) return;
    int s = src[e], d0 = dst[e];
    const float4* pl = (const float4*)&el[s * H];
    const float4* pr = (const float4*)&er[d0 * H];
    float4 l0 = pl[0], l1 = pl[1], r0 = pr[0], r1 = pr[1];
    const int4* pm = (const int4*)&emax[d0 * H];
    int4 m0 = pm[0], m1 = pm[1];
    float ev[8] = {l0.x + r0.x, l0.y + r0.y, l0.z + r0.z, l0.w + r0.w,
                   l1.x + r1.x, l1.y + r1.y, l1.z + r1.z, l1.w + r1.w};
    int mm[8] = {m0.x, m0.y, m0.z, m0.w, m1.x, m1.y, m1.z, m1.w};
#pragma unroll
    for (int h = 0; h < 8; ++h) {
        float v = ev[h];
        v = v >= 0.f ? v : NEG * v;
        float ee = __expf(v - ord2f(mm[h]));
        atomicAdd(&denom[d0 * H + h], ee);
    }
}

// ---- edge pass 3: gat[dst] += a * feat[src], per (edge, head) -----------
__global__ void edge_aggregate(const int* __restrict__ src, const int* __restrict__ dst,
                               const float* __restrict__ el, const float* __restrict__ er,
                               const int* __restrict__ emax, const float* __restrict__ denom,
                               const float* __restrict__ feat, float* __restrict__ gat) {
    int t = blockIdx.x * blockDim.x + threadIdx.x;
    if (t >= N_EDGES * H) return;
    int e = t >> 3, h = t & 7;
    int s = src[e], d0 = dst[e];
    float v = el[s * H + h] + er[d0 * H + h];
    v = v >= 0.f ? v : NEG * v;
    float a = __expf(v - ord2f(emax[d0 * H + h])) / denom[d0 * H + h];
    const float* fs = &feat[s * HD + h * D];
    float* go = &gat[d0 * HD + h * D];
    float4 f0 = *(const float4*)&fs[0];
    float4 f1 = *(const float4*)&fs[4];
    float4 f2 = *(const float4*)&fs[8];
    float4 f3 = *(const float4*)&fs[12];
    float vals[16] = {f0.x, f0.y, f0.z, f0.w, f1.x, f1.y, f1.z, f1.w,
                      f2.x, f2.y, f2.z, f2.w, f3.x, f3.y, f3.z, f3.w};
#pragma unroll
    for (int i = 0; i < 16; ++i) atomicAdd(&go[i], a * vals[i]);
}

// ---- BN stats: per-column sum and sumsq ---------------------------------
__global__ __launch_bounds__(256) void bn_stats(const float* __restrict__ x,
                                                float* __restrict__ sums, int nrows) {
    int c = threadIdx.x & 127;
    int half = threadIdx.x >> 7;  // 0/1
    float s = 0.f, sq = 0.f;
    for (int r = blockIdx.x * 2 + half; r < nrows; r += gridDim.x * 2) {
        float v = x[r * HD + c];
        s += v;
        sq += v * v;
    }
    __shared__ float ls[256], lq[256];
    ls[threadIdx.x] = s;
    lq[threadIdx.x] = sq;
    __syncthreads();
    if (half == 0) {
        atomicAdd(&sums[c], s + ls[c + 128]);
        atomicAdd(&sums[128 + c], sq + lq[c + 128]);
    }
}

// ---- BN apply + ReLU (+ optional residual) ------------------------------
__global__ void bn_apply(const float* __restrict__ x, const float* __restrict__ sums,
                         const float* __restrict__ g, const float* __restrict__ be,
                         const float* __restrict__ res, float* __restrict__ y, int nrows) {
    int t = blockIdx.x * blockDim.x + threadIdx.x;
    if (t >= nrows * 32) return;
    int n = t >> 5, c4 = (t & 31) * 4;
    float invN = 1.0f / (float)nrows;
    float4 v = *(const float4*)&x[n * HD + c4];
    float4 gv = *(const float4*)&g[c4];
    float4 bv = *(const float4*)&be[c4];
    float4 out;
    float* vp = (float*)&v;
    float* gp = (float*)&gv;
    float* bp = (float*)&bv;
    float* op = (float*)&out;
#pragma unroll
    for (int i = 0; i < 4; ++i) {
        int c = c4 + i;
        float mu = sums[c] * invN;
        float var = sums[128 + c] * invN - mu * mu;
        float rstd = rsqrtf(var + EPS);
        float z = (vp[i] - mu) * rstd * gp[i] + bp[i];
        op[i] = z > 0.f ? z : 0.f;
    }
    if (res) {
        float4 rv = *(const float4*)&res[n * HD + c4];
        out.x += rv.x; out.y += rv.y; out.z += rv.z; out.w += rv.w;
    }
    *(float4*)&y[n * HD + c4] = out;
}

// ---- graph sum-pool ------------------------------------------------------
__global__ void pool_sum(const float* __restrict__ h2, const int* __restrict__ gid,
                         float* __restrict__ pooled) {
    int t = blockIdx.x * blockDim.x + threadIdx.x;
    if (t >= N_NODES * 32) return;
    int n = t >> 5, c4 = (t & 31) * 4;
    int g = gid[n];
    float4 v = *(const float4*)&h2[n * HD + c4];
    atomicAdd(&pooled[g * HD + c4 + 0], v.x);
    atomicAdd(&pooled[g * HD + c4 + 1], v.y);
    atomicAdd(&pooled[g * HD + c4 + 2], v.z);
    atomicAdd(&pooled[g * HD + c4 + 3], v.w);
}

// ---- masked prediction head ---------------------------------------------
__global__ void pred_kernel(const float* __restrict__ pooled, const float* __restrict__ W,
                            const float* __restrict__ b, const float* __restrict__ mask,
                            float* __restrict__ out) {
    int t = blockIdx.x * blockDim.x + threadIdx.x;
    if (t >= G_GRAPHS * OUT_DIM) return;
    int g = t >> 6, o = t & 63;
    float acc = b[o];
#pragma unroll 4
    for (int c = 0; c < HD; ++c) {
        float m = mask[o * HD + c] > 0.5f ? 1.f : 0.f;
        acc += pooled[g * HD + c] * W[o * HD + c] * m;
    }
    out[t] = acc;
}

extern "C" void kernel_launch(void* const* d_in, const int* in_sizes, int n_in,
                              void* d_out, int out_size, void* d_ws, size_t ws_size,
                              hipStream_t stream) {
    const float* h   = (const float*)d_in[0];
    const int*   src = (const int*)d_in[1];
    const int*   dst = (const int*)d_in[2];
    const int*   gid = (const int*)d_in[3];
    const float* W0  = (const float*)d_in[4];
    const float* al0 = (const float*)d_in[5];
    const float* ar0 = (const float*)d_in[6];
    // d_in[7] = b0 — BN is shift-invariant, bias cancels exactly
    const float* g0  = (const float*)d_in[8];
    const float* be0 = (const float*)d_in[9];
    const float* W1  = (const float*)d_in[10];
    const float* al1 = (const float*)d_in[11];
    const float* ar1 = (const float*)d_in[12];
    // d_in[13] = b1 — cancels
    const float* g1  = (const float*)d_in[14];
    const float* be1 = (const float*)d_in[15];
    const float* pW  = (const float*)d_in[16];
    const float* pb  = (const float*)d_in[17];
    const float* msk = (const float*)d_in[18];
    float* out = (float*)d_out;

    // workspace layout (fp32 elements)
    float* feat   = (float*)d_ws;                    // [N,128]; reused as h2 at the end
    float* gat    = feat + (size_t)N_NODES * HD;     // [N,128]
    float* h1     = gat + (size_t)N_NODES * HD;      // [N,128]
    float* el     = h1 + (size_t)N_NODES * HD;       // [N,8]
    float* er     = el + (size_t)N_NODES * H;        // [N,8]
    int*   emax   = (int*)(er + (size_t)N_NODES * H);// [N,8]
    float* denom  = (float*)(emax + (size_t)N_NODES * H); // [N,8]
    float* sums   = denom + (size_t)N_NODES * H;     // [256]
    float* pooled = sums + 256;                      // [128,128]

    const int TB = 256;
    dim3 blk(TB);
    int gemm_blocks = (N_NODES + 63) / 64;
    int elr_blocks = (N_NODES * H + TB - 1) / TB;
    int edge_blocks = (N_EDGES + TB - 1) / TB;
    int eagg_blocks = (N_EDGES * H + TB - 1) / TB;
    int app_blocks = (N_NODES * 32 + TB - 1) / TB;

    // ---------------- layer 0 ----------------
    init_layer<<<2048, blk, 0, stream>>>(gat, denom, emax, sums, pooled, 1);
    gemm128<<<gemm_blocks, blk, 0, stream>>>(h, W0, feat, N_NODES);
    compute_elr<<<elr_blocks, blk, 0, stream>>>(feat, al0, ar0, el, er);
    edge_max<<<edge_blocks, blk, 0, stream>>>(src, dst, el, er, emax);
    edge_denom<<<edge_blocks, blk, 0, stream>>>(src, dst, el, er, emax, denom);
    edge_aggregate<<<eagg_blocks, blk, 0, stream>>>(src, dst, el, er, emax, denom, feat, gat);
    bn_stats<<<512, blk, 0, stream>>>(gat, sums, N_NODES);
    bn_apply<<<app_blocks, blk, 0, stream>>>(gat, sums, g0, be0, nullptr, h1, N_NODES);

    // ---------------- layer 1 ----------------
    init_layer<<<2048, blk, 0, stream>>>(gat, denom, emax, sums, pooled, 0);
    gemm128<<<gemm_blocks, blk, 0, stream>>>(h1, W1, feat, N_NODES);
    compute_elr<<<elr_blocks, blk, 0, stream>>>(feat, al1, ar1, el, er);
    edge_max<<<edge_blocks, blk, 0, stream>>>(src, dst, el, er, emax);
    edge_denom<<<edge_blocks, blk, 0, stream>>>(src, dst, el, er, emax, denom);
    edge_aggregate<<<eagg_blocks, blk, 0, stream>>>(src, dst, el, er, emax, denom, feat, gat);
    bn_stats<<<512, blk, 0, stream>>>(gat, sums, N_NODES);
    // h2 = relu(bn(gat)) + h1, written over feat
    bn_apply<<<app_blocks, blk, 0, stream>>>(gat, sums, g1, be1, h1, feat, N_NODES);

    // ---------------- pool + head ----------------
    pool_sum<<<app_blocks, blk, 0, stream>>>(feat, gid, pooled);
    pred_kernel<<<(G_GRAPHS * OUT_DIM + TB - 1) / TB, blk, 0, stream>>>(pooled, pW, pb, msk, out);
}

// Round 2
// 1147.131 us; speedup vs baseline: 22.7156x; 22.7156x over previous
//
#include <hip/hip_runtime.h>
#include <cstdint>

#define N_NODES 100000
#define N_EDGES 1600000
#define H 8
#define D 16
#define HD 128
#define G_GRAPHS 128
#define OUT_DIM 64
#define EPS 1e-3f
#define NEG 0.2f
#define SCAN_BLOCKS 98   // ceil(100000/1024)

// ---- init: zero deg (aliased over el), pooled ---------------------------
__global__ void init_all(int* __restrict__ deg, float* __restrict__ pooled) {
    int tid = blockIdx.x * blockDim.x + threadIdx.x;
    int stride = gridDim.x * blockDim.x;
    for (int i = tid; i < N_NODES; i += stride) deg[i] = 0;
    for (int i = tid; i < G_GRAPHS * HD; i += stride) pooled[i] = 0.f;
}

__global__ void zero256(float* __restrict__ sums) {
    sums[threadIdx.x] = 0.f;
}

// ---- CSR build ----------------------------------------------------------
__global__ void hist_kernel(const int* __restrict__ dst, int* __restrict__ deg) {
    int e = blockIdx.x * blockDim.x + threadIdx.x;
    if (e < N_EDGES) atomicAdd(&deg[dst[e]], 1);
}

__global__ __launch_bounds__(256) void scan1(const int* __restrict__ deg,
                                             int* __restrict__ offs,
                                             int* __restrict__ blksum) {
    __shared__ int bufA[256], bufB[256];
    int t = threadIdx.x;
    int base = blockIdx.x * 1024;
    int idx = base + t * 4;
    int v[4];
#pragma unroll
    for (int i = 0; i < 4; ++i) v[i] = (idx + i < N_NODES) ? deg[idx + i] : 0;
    int s = v[0] + v[1] + v[2] + v[3];
    bufA[t] = s;
    __syncthreads();
    int* a = bufA; int* b = bufB;
    for (int off = 1; off < 256; off <<= 1) {
        int val = a[t];
        if (t >= off) val += a[t - off];
        b[t] = val;
        __syncthreads();
        int* c = a; a = b; b = c;
    }
    int excl = a[t] - s;  // exclusive prefix of this thread's chunk
#pragma unroll
    for (int i = 0; i < 4; ++i) {
        if (idx + i < N_NODES) offs[idx + i] = excl;
        excl += v[i];
    }
    if (t == 255) blksum[blockIdx.x] = a[255];
}

__global__ void scan2(const int* __restrict__ blksum, int* __restrict__ blkoff) {
    __shared__ int bufA[128], bufB[128];
    int t = threadIdx.x;  // 128 threads
    int v = (t < SCAN_BLOCKS) ? blksum[t] : 0;
    bufA[t] = v;
    __syncthreads();
    int* a = bufA; int* b = bufB;
    for (int off = 1; off < 128; off <<= 1) {
        int val = a[t];
        if (t >= off) val += a[t - off];
        b[t] = val;
        __syncthreads();
        int* c = a; a = b; b = c;
    }
    if (t < SCAN_BLOCKS) blkoff[t] = a[t] - v;  // exclusive
}

__global__ __launch_bounds__(256) void scan3(int* __restrict__ offs,
                                             const int* __restrict__ blkoff,
                                             int* __restrict__ cursor) {
    int base = blockIdx.x * 1024;
    int add = blkoff[blockIdx.x];
#pragma unroll
    for (int i = 0; i < 4; ++i) {
        int idx = base + threadIdx.x + i * 256;
        if (idx < N_NODES) {
            int o = offs[idx] + add;
            offs[idx] = o;
            cursor[idx] = o;
        }
    }
}

__global__ void scatter_kernel(const int* __restrict__ src, const int* __restrict__ dst,
                               int* __restrict__ cursor, int* __restrict__ csr_src) {
    int e = blockIdx.x * blockDim.x + threadIdx.x;
    if (e >= N_EDGES) return;
    int d0 = dst[e];
    int p = atomicAdd(&cursor[d0], 1);
    csr_src[p] = src[e];
}
// After scatter: cursor[n] == end offset of node n; offs[n] == begin.

// ---- feat = X @ W  (X:[nrows,128], W:[128,128]) -------------------------
__global__ __launch_bounds__(256) void gemm128(const float* __restrict__ X,
                                               const float* __restrict__ W,
                                               float* __restrict__ Y, int nrows) {
    __shared__ float Ws[HD * HD];
    __shared__ float xs[8][HD];
    for (int i = threadIdx.x; i < HD * HD; i += 256) Ws[i] = W[i];
    int c4 = (threadIdx.x & 31) * 4;
    int rs = threadIdx.x >> 5;  // 0..7
    int base = blockIdx.x * 64;
    for (int it = 0; it < 8; ++it) {
        int r0 = base + it * 8;
        __syncthreads();
        {
            int lr = r0 + (threadIdx.x >> 5);
            int lc = (threadIdx.x & 31) * 4;
            if (lr < nrows) *(float4*)&xs[threadIdx.x >> 5][lc] = *(const float4*)&X[lr * HD + lc];
        }
        __syncthreads();
        int r = r0 + rs;
        if (r < nrows) {
            float4 acc = {0.f, 0.f, 0.f, 0.f};
#pragma unroll
            for (int k = 0; k < HD; ++k) {
                float xv = xs[rs][k];
                float4 w = *(float4*)&Ws[k * HD + c4];
                acc.x += xv * w.x; acc.y += xv * w.y;
                acc.z += xv * w.z; acc.w += xv * w.w;
            }
            *(float4*)&Y[r * HD + c4] = acc;
        }
    }
}

// ---- el/er: per (node, head) dot of feat with attn vectors --------------
__global__ void compute_elr(const float* __restrict__ feat, const float* __restrict__ al,
                            const float* __restrict__ ar, float* __restrict__ el,
                            float* __restrict__ er) {
    int t = blockIdx.x * blockDim.x + threadIdx.x;
    if (t >= N_NODES * H) return;
    int n = t >> 3, h = t & 7;
    const float4* f = (const float4*)&feat[n * HD + h * D];
    const float4* a = (const float4*)&al[h * D];
    const float4* b = (const float4*)&ar[h * D];
    float sl = 0.f, sr = 0.f;
#pragma unroll
    for (int i = 0; i < 4; ++i) {
        float4 fv = f[i], av = a[i], bv = b[i];
        sl += fv.x * av.x + fv.y * av.y + fv.z * av.z + fv.w * av.w;
        sr += fv.x * bv.x + fv.y * bv.y + fv.z * bv.z + fv.w * bv.w;
    }
    el[t] = sl;
    er[t] = sr;
}

// ---- per-dst-node GAT softmax + aggregate: one wave per node ------------
__global__ __launch_bounds__(256) void gat_node(const int* __restrict__ offs,
                                                const int* __restrict__ ends,
                                                const int* __restrict__ csr_src,
                                                const float* __restrict__ el,
                                                const float* __restrict__ er,
                                                const float* __restrict__ feat,
                                                float* __restrict__ gat) {
    int node = blockIdx.x * 4 + (threadIdx.x >> 6);
    if (node >= N_NODES) return;
    int lane = threadIdx.x & 63;
    int beg = offs[node], end = ends[node];
    // phase 1: lane = j*8 + h  (h fastest => coalesced el row reads)
    int h = lane & 7, j = lane >> 3;
    float ern = er[node * H + h];
    float m = -1e30f;
    for (int p = beg + j; p < end; p += 8) {
        int s = csr_src[p];
        float v = el[s * H + h] + ern;
        v = v >= 0.f ? v : NEG * v;
        m = fmaxf(m, v);
    }
    m = fmaxf(m, __shfl_xor(m, 8));
    m = fmaxf(m, __shfl_xor(m, 16));
    m = fmaxf(m, __shfl_xor(m, 32));
    float dsum = 0.f;
    for (int p = beg + j; p < end; p += 8) {
        int s = csr_src[p];
        float v = el[s * H + h] + ern;
        v = v >= 0.f ? v : NEG * v;
        dsum += __expf(v - m);
    }
    dsum += __shfl_xor(dsum, 8);
    dsum += __shfl_xor(dsum, 16);
    dsum += __shfl_xor(dsum, 32);
    // lanes 0..7 hold (m, dsum) for heads 0..7
    int h0 = lane >> 4;      // head of column c0 = lane
    int h1 = h0 + 4;         // head of column c1 = lane + 64
    float m0 = __shfl(m, h0), m1 = __shfl(m, h1);
    float id0 = 1.f / __shfl(dsum, h0);
    float id1 = 1.f / __shfl(dsum, h1);
    float er0 = er[node * H + h0], er1 = er[node * H + h1];
    float acc0 = 0.f, acc1 = 0.f;
    for (int p = beg; p < end; ++p) {
        int s = csr_src[p];
        float v0 = el[s * H + h0] + er0;
        v0 = v0 >= 0.f ? v0 : NEG * v0;
        float a0 = __expf(v0 - m0) * id0;
        float v1 = el[s * H + h1] + er1;
        v1 = v1 >= 0.f ? v1 : NEG * v1;
        float a1 = __expf(v1 - m1) * id1;
        acc0 += a0 * feat[s * HD + lane];
        acc1 += a1 * feat[s * HD + 64 + lane];
    }
    gat[node * HD + lane] = acc0;
    gat[node * HD + 64 + lane] = acc1;
}

// ---- BN stats: per-column sum and sumsq ---------------------------------
__global__ __launch_bounds__(256) void bn_stats(const float* __restrict__ x,
                                                float* __restrict__ sums, int nrows) {
    int c = threadIdx.x & 127;
    int half = threadIdx.x >> 7;  // 0/1
    float s = 0.f, sq = 0.f;
    for (int r = blockIdx.x * 2 + half; r < nrows; r += gridDim.x * 2) {
        float v = x[r * HD + c];
        s += v;
        sq += v * v;
    }
    __shared__ float ls[256], lq[256];
    ls[threadIdx.x] = s;
    lq[threadIdx.x] = sq;
    __syncthreads();
    if (half == 0) {
        atomicAdd(&sums[c], s + ls[c + 128]);
        atomicAdd(&sums[128 + c], sq + lq[c + 128]);
    }
}

// ---- BN apply + ReLU (+ optional residual) ------------------------------
__global__ void bn_apply(const float* __restrict__ x, const float* __restrict__ sums,
                         const float* __restrict__ g, const float* __restrict__ be,
                         const float* __restrict__ res, float* __restrict__ y, int nrows) {
    int t = blockIdx.x * blockDim.x + threadIdx.x;
    if (t >= nrows * 32) return;
    int n = t >> 5, c4 = (t & 31) * 4;
    float invN = 1.0f / (float)nrows;
    float4 v = *(const float4*)&x[n * HD + c4];
    float4 gv = *(const float4*)&g[c4];
    float4 bv = *(const float4*)&be[c4];
    float4 out;
    float* vp = (float*)&v;
    float* gp = (float*)&gv;
    float* bp = (float*)&bv;
    float* op = (float*)&out;
#pragma unroll
    for (int i = 0; i < 4; ++i) {
        int c = c4 + i;
        float mu = sums[c] * invN;
        float var = sums[128 + c] * invN - mu * mu;
        float rstd = rsqrtf(var + EPS);
        float z = (vp[i] - mu) * rstd * gp[i] + bp[i];
        op[i] = z > 0.f ? z : 0.f;
    }
    if (res) {
        float4 rv = *(const float4*)&res[n * HD + c4];
        out.x += rv.x; out.y += rv.y; out.z += rv.z; out.w += rv.w;
    }
    *(float4*)&y[n * HD + c4] = out;
}

// ---- graph sum-pool: gid is SORTED, run-detect then few atomics ---------
__global__ void pool_sum2(const float* __restrict__ h2, const int* __restrict__ gid,
                          float* __restrict__ pooled) {
    int t = threadIdx.x;  // 128 threads, thread owns column t
    int r0 = blockIdx.x * 256;
    int r1 = r0 + 256 < N_NODES ? r0 + 256 : N_NODES;
    if (r0 >= N_NODES) return;
    float acc = 0.f;
    int cur = gid[r0];
    for (int r = r0; r < r1; ++r) {
        int g = gid[r];
        if (g != cur) {
            atomicAdd(&pooled[cur * HD + t], acc);
            acc = 0.f;
            cur = g;
        }
        acc += h2[r * HD + t];
    }
    atomicAdd(&pooled[cur * HD + t], acc);
}

// ---- masked prediction head ---------------------------------------------
__global__ void pred_kernel(const float* __restrict__ pooled, const float* __restrict__ W,
                            const float* __restrict__ b, const float* __restrict__ mask,
                            float* __restrict__ out) {
    int t = blockIdx.x * blockDim.x + threadIdx.x;
    if (t >= G_GRAPHS * OUT_DIM) return;
    int g = t >> 6, o = t & 63;
    float acc = b[o];
#pragma unroll 4
    for (int c = 0; c < HD; ++c) {
        float m = mask[o * HD + c] > 0.5f ? 1.f : 0.f;
        acc += pooled[g * HD + c] * W[o * HD + c] * m;
    }
    out[t] = acc;
}

extern "C" void kernel_launch(void* const* d_in, const int* in_sizes, int n_in,
                              void* d_out, int out_size, void* d_ws, size_t ws_size,
                              hipStream_t stream) {
    const float* h   = (const float*)d_in[0];
    const int*   src = (const int*)d_in[1];
    const int*   dst = (const int*)d_in[2];
    const int*   gid = (const int*)d_in[3];
    const float* W0  = (const float*)d_in[4];
    const float* al0 = (const float*)d_in[5];
    const float* ar0 = (const float*)d_in[6];
    // d_in[7] = b0 — BN is shift-invariant, bias cancels exactly
    const float* g0  = (const float*)d_in[8];
    const float* be0 = (const float*)d_in[9];
    const float* W1  = (const float*)d_in[10];
    const float* al1 = (const float*)d_in[11];
    const float* ar1 = (const float*)d_in[12];
    // d_in[13] = b1 — cancels
    const float* g1  = (const float*)d_in[14];
    const float* be1 = (const float*)d_in[15];
    const float* pW  = (const float*)d_in[16];
    const float* pb  = (const float*)d_in[17];
    const float* msk = (const float*)d_in[18];
    float* out = (float*)d_out;

    // workspace layout (fp32 elements)
    float* feat   = (float*)d_ws;                      // [N,128]; reused as h2 at end
    float* gat    = feat + (size_t)N_NODES * HD;       // [N,128]
    float* h1     = gat + (size_t)N_NODES * HD;        // [N,128]
    float* el     = h1 + (size_t)N_NODES * HD;         // [N,8]
    float* er     = el + (size_t)N_NODES * H;          // [N,8]
    int*   offs   = (int*)(er + (size_t)N_NODES * H);  // [N]
    int*   cursor = offs + N_NODES;                    // [N] -> becomes end offsets
    int*   csr_src= cursor + N_NODES;                  // [E]
    int*   blksum = csr_src + N_EDGES;                 // [128]
    int*   blkoff = blksum + 128;                      // [128]
    float* sums   = (float*)(blkoff + 128);            // [256]
    float* pooled = sums + 256;                        // [128,128]
    int*   deg    = (int*)el;                          // alias: dead before el written

    const int TB = 256;
    dim3 blk(TB);
    int gemm_blocks = (N_NODES + 63) / 64;
    int elr_blocks  = (N_NODES * H + TB - 1) / TB;
    int edge_blocks = (N_EDGES + TB - 1) / TB;
    int node_blocks = (N_NODES + 3) / 4;
    int app_blocks  = (N_NODES * 32 + TB - 1) / TB;
    int pool_blocks = (N_NODES + 255) / 256;

    // ---------------- CSR build (shared by both layers) ----------------
    init_all<<<512, blk, 0, stream>>>(deg, pooled);
    hist_kernel<<<edge_blocks, blk, 0, stream>>>(dst, deg);
    scan1<<<SCAN_BLOCKS, blk, 0, stream>>>(deg, offs, blksum);
    scan2<<<1, 128, 0, stream>>>(blksum, blkoff);
    scan3<<<SCAN_BLOCKS, blk, 0, stream>>>(offs, blkoff, cursor);
    scatter_kernel<<<edge_blocks, blk, 0, stream>>>(src, dst, cursor, csr_src);

    // ---------------- layer 0 ----------------
    gemm128<<<gemm_blocks, blk, 0, stream>>>(h, W0, feat, N_NODES);
    compute_elr<<<elr_blocks, blk, 0, stream>>>(feat, al0, ar0, el, er);
    gat_node<<<node_blocks, blk, 0, stream>>>(offs, cursor, csr_src, el, er, feat, gat);
    zero256<<<1, 256, 0, stream>>>(sums);
    bn_stats<<<512, blk, 0, stream>>>(gat, sums, N_NODES);
    bn_apply<<<app_blocks, blk, 0, stream>>>(gat, sums, g0, be0, nullptr, h1, N_NODES);

    // ---------------- layer 1 ----------------
    gemm128<<<gemm_blocks, blk, 0, stream>>>(h1, W1, feat, N_NODES);
    compute_elr<<<elr_blocks, blk, 0, stream>>>(feat, al1, ar1, el, er);
    gat_node<<<node_blocks, blk, 0, stream>>>(offs, cursor, csr_src, el, er, feat, gat);
    zero256<<<1, 256, 0, stream>>>(sums);
    bn_stats<<<512, blk, 0, stream>>>(gat, sums, N_NODES);
    // h2 = relu(bn(gat)) + h1, written over feat
    bn_apply<<<app_blocks, blk, 0, stream>>>(gat, sums, g1, be1, h1, feat, N_NODES);

    // ---------------- pool + head ----------------
    pool_sum2<<<pool_blocks, 128, 0, stream>>>(feat, gid, pooled);
    pred_kernel<<<(G_GRAPHS * OUT_DIM + TB - 1) / TB, blk, 0, stream>>>(pooled, pW, pb, msk, out);
}

// Round 3
// 889.687 us; speedup vs baseline: 29.2888x; 1.2894x over previous
//
#include <hip/hip_runtime.h>
#include <cstdint>

#define N_NODES 100000
#define N_EDGES 1600000
#define H 8
#define D 16
#define HD 128
#define G_GRAPHS 128
#define OUT_DIM 64
#define EPS 1e-3f
#define NEG 0.2f
#define SCAN_BLOCKS 98   // ceil(100000/1024)

__device__ __forceinline__ float bf2f(unsigned short u) {
    return __uint_as_float(((unsigned)u) << 16);
}
__device__ __forceinline__ unsigned short f2bf(float x) {
    unsigned u = __float_as_uint(x);
    unsigned r = (u + 0x7FFFu + ((u >> 16) & 1u)) >> 16;  // RTNE
    return (unsigned short)r;
}

// ---- init: zero deg (aliased over el), pooled ---------------------------
__global__ void init_all(int* __restrict__ deg, float* __restrict__ pooled) {
    int tid = blockIdx.x * blockDim.x + threadIdx.x;
    int stride = gridDim.x * blockDim.x;
    for (int i = tid; i < N_NODES; i += stride) deg[i] = 0;
    for (int i = tid; i < G_GRAPHS * HD; i += stride) pooled[i] = 0.f;
}

__global__ void zero256(float* __restrict__ sums) {
    sums[threadIdx.x] = 0.f;
}

// ---- CSR build ----------------------------------------------------------
__global__ void hist_kernel(const int* __restrict__ dst, int* __restrict__ deg) {
    int t = blockIdx.x * blockDim.x + threadIdx.x;
    int e = t * 4;
    if (e + 3 < N_EDGES) {
        int4 d4 = *(const int4*)&dst[e];
        atomicAdd(&deg[d4.x], 1);
        atomicAdd(&deg[d4.y], 1);
        atomicAdd(&deg[d4.z], 1);
        atomicAdd(&deg[d4.w], 1);
    } else {
        for (int i = e; i < N_EDGES; ++i) atomicAdd(&deg[dst[i]], 1);
    }
}

__global__ __launch_bounds__(256) void scan1(const int* __restrict__ deg,
                                             int* __restrict__ offs,
                                             int* __restrict__ blksum) {
    __shared__ int bufA[256], bufB[256];
    int t = threadIdx.x;
    int base = blockIdx.x * 1024;
    int idx = base + t * 4;
    int v[4];
#pragma unroll
    for (int i = 0; i < 4; ++i) v[i] = (idx + i < N_NODES) ? deg[idx + i] : 0;
    int s = v[0] + v[1] + v[2] + v[3];
    bufA[t] = s;
    __syncthreads();
    int* a = bufA; int* b = bufB;
    for (int off = 1; off < 256; off <<= 1) {
        int val = a[t];
        if (t >= off) val += a[t - off];
        b[t] = val;
        __syncthreads();
        int* c = a; a = b; b = c;
    }
    int excl = a[t] - s;
#pragma unroll
    for (int i = 0; i < 4; ++i) {
        if (idx + i < N_NODES) offs[idx + i] = excl;
        excl += v[i];
    }
    if (t == 255) blksum[blockIdx.x] = a[255];
}

__global__ void scan2(const int* __restrict__ blksum, int* __restrict__ blkoff) {
    __shared__ int bufA[128], bufB[128];
    int t = threadIdx.x;  // 128 threads
    int v = (t < SCAN_BLOCKS) ? blksum[t] : 0;
    bufA[t] = v;
    __syncthreads();
    int* a = bufA; int* b = bufB;
    for (int off = 1; off < 128; off <<= 1) {
        int val = a[t];
        if (t >= off) val += a[t - off];
        b[t] = val;
        __syncthreads();
        int* c = a; a = b; b = c;
    }
    if (t < SCAN_BLOCKS) blkoff[t] = a[t] - v;
}

__global__ __launch_bounds__(256) void scan3(int* __restrict__ offs,
                                             const int* __restrict__ blkoff,
                                             int* __restrict__ cursor) {
    int base = blockIdx.x * 1024;
    int add = blkoff[blockIdx.x];
#pragma unroll
    for (int i = 0; i < 4; ++i) {
        int idx = base + threadIdx.x + i * 256;
        if (idx < N_NODES) {
            int o = offs[idx] + add;
            offs[idx] = o;
            cursor[idx] = o;
        }
    }
}

__global__ void scatter_kernel(const int* __restrict__ src, const int* __restrict__ dst,
                               int* __restrict__ cursor, int* __restrict__ csr_src) {
    int e = blockIdx.x * blockDim.x + threadIdx.x;
    if (e >= N_EDGES) return;
    int d0 = dst[e];
    int p = atomicAdd(&cursor[d0], 1);
    csr_src[p] = src[e];
}
// After scatter: cursor[n] == end offset of node n; offs[n] == begin.

// ---- feat_bf16 = bf16(X @ W)  (X:[nrows,128] fp32, W:[128,128]) ---------
__global__ __launch_bounds__(256) void gemm128(const float* __restrict__ X,
                                               const float* __restrict__ W,
                                               unsigned short* __restrict__ Yb,
                                               int nrows) {
    __shared__ float Ws[HD * HD];
    __shared__ float xs[8][HD];
    for (int i = threadIdx.x; i < HD * HD; i += 256) Ws[i] = W[i];
    int c4 = (threadIdx.x & 31) * 4;
    int rs = threadIdx.x >> 5;  // 0..7
    int base = blockIdx.x * 64;
    for (int it = 0; it < 8; ++it) {
        int r0 = base + it * 8;
        __syncthreads();
        {
            int lr = r0 + (threadIdx.x >> 5);
            int lc = (threadIdx.x & 31) * 4;
            if (lr < nrows) *(float4*)&xs[threadIdx.x >> 5][lc] = *(const float4*)&X[lr * HD + lc];
        }
        __syncthreads();
        int r = r0 + rs;
        if (r < nrows) {
            float4 acc = {0.f, 0.f, 0.f, 0.f};
#pragma unroll
            for (int k = 0; k < HD; ++k) {
                float xv = xs[rs][k];
                float4 w = *(float4*)&Ws[k * HD + c4];
                acc.x += xv * w.x; acc.y += xv * w.y;
                acc.z += xv * w.z; acc.w += xv * w.w;
            }
            ushort4 o;
            o.x = f2bf(acc.x); o.y = f2bf(acc.y);
            o.z = f2bf(acc.z); o.w = f2bf(acc.w);
            *(ushort4*)&Yb[r * HD + c4] = o;
        }
    }
}

// ---- el/er from bf16 feat -----------------------------------------------
__global__ void compute_elr(const unsigned short* __restrict__ featb,
                            const float* __restrict__ al,
                            const float* __restrict__ ar, float* __restrict__ el,
                            float* __restrict__ er) {
    int t = blockIdx.x * blockDim.x + threadIdx.x;
    if (t >= N_NODES * H) return;
    int n = t >> 3, h = t & 7;
    const unsigned* fp = (const unsigned*)&featb[n * HD + h * D];
    const float* ap = &al[h * D];
    const float* bp = &ar[h * D];
    float sl = 0.f, sr = 0.f;
#pragma unroll
    for (int i = 0; i < 8; ++i) {
        unsigned u = fp[i];
        float f0 = bf2f((unsigned short)(u & 0xFFFFu));
        float f1 = bf2f((unsigned short)(u >> 16));
        sl += f0 * ap[2 * i] + f1 * ap[2 * i + 1];
        sr += f0 * bp[2 * i] + f1 * bp[2 * i + 1];
    }
    el[t] = sl;
    er[t] = sr;
}

// ---- per-dst-node GAT softmax + aggregate: one wave per node ------------
// No max-subtraction (|e| <~ 5, exp safe). Weights computed once per
// (edge, head) and shuffle-broadcast; messages gathered in bf16.
__global__ __launch_bounds__(256) void gat_node(const int* __restrict__ offs,
                                                const int* __restrict__ ends,
                                                const int* __restrict__ csr_src,
                                                const float* __restrict__ el,
                                                const float* __restrict__ er,
                                                const unsigned short* __restrict__ featb,
                                                float* __restrict__ gat) {
    int node = blockIdx.x * 4 + (threadIdx.x >> 6);
    if (node >= N_NODES) return;
    int lane = threadIdx.x & 63;
    int beg = offs[node], end = ends[node];
    int h = lane & 7, j = lane >> 3;  // j: edge slot AND my column-pair's head
    float ern = er[node * H + h];
    // pass 1: denom for head h
    float dsum = 0.f;
    for (int p = beg + j; p < end; p += 8) {
        int s = csr_src[p];
        float v = el[s * H + h] + ern;
        v = v >= 0.f ? v : NEG * v;
        dsum += __expf(v);
    }
    dsum += __shfl_xor(dsum, 8);
    dsum += __shfl_xor(dsum, 16);
    dsum += __shfl_xor(dsum, 32);
    float invd = 1.f / dsum;
    // pass 2: accumulate columns 2*lane, 2*lane+1 (head = lane>>3 == j)
    float accx = 0.f, accy = 0.f;
    for (int p0 = beg; p0 < end; p0 += 8) {
        int cnt = end - p0;
        if (cnt > 8) cnt = 8;
        float w = 0.f;
        int sj = 0;
        if (j < cnt) {
            sj = csr_src[p0 + j];
            float v = el[sj * H + h] + ern;
            v = v >= 0.f ? v : NEG * v;
            w = __expf(v) * invd;
        }
        if (cnt == 8) {
#pragma unroll
            for (int j2 = 0; j2 < 8; ++j2) {
                int s = __shfl(sj, j2 * 8);
                float wv = __shfl(w, j2 * 8 + j);
                unsigned pair = *(const unsigned*)&featb[s * HD + lane * 2];
                accx += wv * bf2f((unsigned short)(pair & 0xFFFFu));
                accy += wv * bf2f((unsigned short)(pair >> 16));
            }
        } else {
            for (int j2 = 0; j2 < cnt; ++j2) {
                int s = __shfl(sj, j2 * 8);
                float wv = __shfl(w, j2 * 8 + j);
                unsigned pair = *(const unsigned*)&featb[s * HD + lane * 2];
                accx += wv * bf2f((unsigned short)(pair & 0xFFFFu));
                accy += wv * bf2f((unsigned short)(pair >> 16));
            }
        }
    }
    float2 o; o.x = accx; o.y = accy;
    *(float2*)&gat[node * HD + lane * 2] = o;
}

// ---- BN stats: per-column sum and sumsq ---------------------------------
__global__ __launch_bounds__(256) void bn_stats(const float* __restrict__ x,
                                                float* __restrict__ sums, int nrows) {
    int c = threadIdx.x & 127;
    int half = threadIdx.x >> 7;  // 0/1
    float s = 0.f, sq = 0.f;
    for (int r = blockIdx.x * 2 + half; r < nrows; r += gridDim.x * 2) {
        float v = x[r * HD + c];
        s += v;
        sq += v * v;
    }
    __shared__ float ls[256], lq[256];
    ls[threadIdx.x] = s;
    lq[threadIdx.x] = sq;
    __syncthreads();
    if (half == 0) {
        atomicAdd(&sums[c], s + ls[c + 128]);
        atomicAdd(&sums[128 + c], sq + lq[c + 128]);
    }
}

// ---- BN apply + ReLU (+ optional residual) ------------------------------
__global__ void bn_apply(const float* __restrict__ x, const float* __restrict__ sums,
                         const float* __restrict__ g, const float* __restrict__ be,
                         const float* __restrict__ res, float* __restrict__ y, int nrows) {
    int t = blockIdx.x * blockDim.x + threadIdx.x;
    if (t >= nrows * 32) return;
    int n = t >> 5, c4 = (t & 31) * 4;
    float invN = 1.0f / (float)nrows;
    float4 v = *(const float4*)&x[n * HD + c4];
    float4 gv = *(const float4*)&g[c4];
    float4 bv = *(const float4*)&be[c4];
    float4 out;
    float* vp = (float*)&v;
    float* gp = (float*)&gv;
    float* bp = (float*)&bv;
    float* op = (float*)&out;
#pragma unroll
    for (int i = 0; i < 4; ++i) {
        int c = c4 + i;
        float mu = sums[c] * invN;
        float var = sums[128 + c] * invN - mu * mu;
        float rstd = rsqrtf(var + EPS);
        float z = (vp[i] - mu) * rstd * gp[i] + bp[i];
        op[i] = z > 0.f ? z : 0.f;
    }
    if (res) {
        float4 rv = *(const float4*)&res[n * HD + c4];
        out.x += rv.x; out.y += rv.y; out.z += rv.z; out.w += rv.w;
    }
    *(float4*)&y[n * HD + c4] = out;
}

// ---- graph sum-pool: gid is SORTED, run-detect then few atomics ---------
__global__ void pool_sum2(const float* __restrict__ h2, const int* __restrict__ gid,
                          float* __restrict__ pooled) {
    int t = threadIdx.x;  // 128 threads, thread owns column t
    int r0 = blockIdx.x * 256;
    int r1 = r0 + 256 < N_NODES ? r0 + 256 : N_NODES;
    if (r0 >= N_NODES) return;
    float acc = 0.f;
    int cur = gid[r0];
    for (int r = r0; r < r1; ++r) {
        int g = gid[r];
        if (g != cur) {
            atomicAdd(&pooled[cur * HD + t], acc);
            acc = 0.f;
            cur = g;
        }
        acc += h2[r * HD + t];
    }
    atomicAdd(&pooled[cur * HD + t], acc);
}

// ---- masked prediction head ---------------------------------------------
__global__ void pred_kernel(const float* __restrict__ pooled, const float* __restrict__ W,
                            const float* __restrict__ b, const float* __restrict__ mask,
                            float* __restrict__ out) {
    int t = blockIdx.x * blockDim.x + threadIdx.x;
    if (t >= G_GRAPHS * OUT_DIM) return;
    int g = t >> 6, o = t & 63;
    float acc = b[o];
#pragma unroll 4
    for (int c = 0; c < HD; ++c) {
        float m = mask[o * HD + c] > 0.5f ? 1.f : 0.f;
        acc += pooled[g * HD + c] * W[o * HD + c] * m;
    }
    out[t] = acc;
}

extern "C" void kernel_launch(void* const* d_in, const int* in_sizes, int n_in,
                              void* d_out, int out_size, void* d_ws, size_t ws_size,
                              hipStream_t stream) {
    const float* h   = (const float*)d_in[0];
    const int*   src = (const int*)d_in[1];
    const int*   dst = (const int*)d_in[2];
    const int*   gid = (const int*)d_in[3];
    const float* W0  = (const float*)d_in[4];
    const float* al0 = (const float*)d_in[5];
    const float* ar0 = (const float*)d_in[6];
    // d_in[7] = b0 — BN shift-invariance: bias cancels exactly
    const float* g0  = (const float*)d_in[8];
    const float* be0 = (const float*)d_in[9];
    const float* W1  = (const float*)d_in[10];
    const float* al1 = (const float*)d_in[11];
    const float* ar1 = (const float*)d_in[12];
    // d_in[13] = b1 — cancels
    const float* g1  = (const float*)d_in[14];
    const float* be1 = (const float*)d_in[15];
    const float* pW  = (const float*)d_in[16];
    const float* pb  = (const float*)d_in[17];
    const float* msk = (const float*)d_in[18];
    float* out = (float*)d_out;

    // workspace layout
    float* gat    = (float*)d_ws;                      // [N,128] fp32; h2 at end
    float* h1     = gat + (size_t)N_NODES * HD;        // [N,128] fp32
    float* el     = h1 + (size_t)N_NODES * HD;         // [N,8]
    float* er     = el + (size_t)N_NODES * H;          // [N,8]
    int*   offs   = (int*)(er + (size_t)N_NODES * H);  // [N]
    int*   cursor = offs + N_NODES;                    // [N] -> end offsets
    int*   csr_src= cursor + N_NODES;                  // [E]
    int*   blksum = csr_src + N_EDGES;                 // [128]
    int*   blkoff = blksum + 128;                      // [128]
    float* sums   = (float*)(blkoff + 128);            // [256]
    float* pooled = sums + 256;                        // [128,128]
    unsigned short* featb = (unsigned short*)(pooled + G_GRAPHS * HD); // [N,128] bf16
    int*   deg    = (int*)el;  // alias: dead before el written

    const int TB = 256;
    dim3 blk(TB);
    int gemm_blocks = (N_NODES + 63) / 64;
    int elr_blocks  = (N_NODES * H + TB - 1) / TB;
    int edge_blocks = (N_EDGES + TB - 1) / TB;
    int hist_blocks = (N_EDGES / 4 + TB - 1) / TB;
    int node_blocks = (N_NODES + 3) / 4;
    int app_blocks  = (N_NODES * 32 + TB - 1) / TB;
    int pool_blocks = (N_NODES + 255) / 256;

    // ---------------- CSR build (shared by both layers) ----------------
    init_all<<<512, blk, 0, stream>>>(deg, pooled);
    hist_kernel<<<hist_blocks, blk, 0, stream>>>(dst, deg);
    scan1<<<SCAN_BLOCKS, blk, 0, stream>>>(deg, offs, blksum);
    scan2<<<1, 128, 0, stream>>>(blksum, blkoff);
    scan3<<<SCAN_BLOCKS, blk, 0, stream>>>(offs, blkoff, cursor);
    scatter_kernel<<<edge_blocks, blk, 0, stream>>>(src, dst, cursor, csr_src);

    // ---------------- layer 0 ----------------
    gemm128<<<gemm_blocks, blk, 0, stream>>>(h, W0, featb, N_NODES);
    compute_elr<<<elr_blocks, blk, 0, stream>>>(featb, al0, ar0, el, er);
    gat_node<<<node_blocks, blk, 0, stream>>>(offs, cursor, csr_src, el, er, featb, gat);
    zero256<<<1, 256, 0, stream>>>(sums);
    bn_stats<<<512, blk, 0, stream>>>(gat, sums, N_NODES);
    bn_apply<<<app_blocks, blk, 0, stream>>>(gat, sums, g0, be0, nullptr, h1, N_NODES);

    // ---------------- layer 1 ----------------
    gemm128<<<gemm_blocks, blk, 0, stream>>>(h1, W1, featb, N_NODES);
    compute_elr<<<elr_blocks, blk, 0, stream>>>(featb, al1, ar1, el, er);
    gat_node<<<node_blocks, blk, 0, stream>>>(offs, cursor, csr_src, el, er, featb, gat);
    zero256<<<1, 256, 0, stream>>>(sums);
    bn_stats<<<512, blk, 0, stream>>>(gat, sums, N_NODES);
    // h2 = relu(bn(gat)) + h1, in-place over gat (elementwise-safe)
    bn_apply<<<app_blocks, blk, 0, stream>>>(gat, sums, g1, be1, h1, gat, N_NODES);

    // ---------------- pool + head ----------------
    pool_sum2<<<pool_blocks, 128, 0, stream>>>(gat, gid, pooled);
    pred_kernel<<<(G_GRAPHS * OUT_DIM + TB - 1) / TB, blk, 0, stream>>>(pooled, pW, pb, msk, out);
}

// Round 4
// 731.164 us; speedup vs baseline: 35.6388x; 1.2168x over previous
//
#include <hip/hip_runtime.h>
#include <cstdint>

#define N_NODES 100000
#define N_EDGES 1600000
#define H 8
#define D 16
#define HD 128
#define G_GRAPHS 128
#define OUT_DIM 64
#define EPS 1e-3f
#define NEG 0.2f
#define SCAN_BLOCKS 98   // ceil(100000/1024)
#define NBUCK 196        // ceil(100000/512) dst buckets
#define BSHIFT 9         // 512 nodes per bucket
#define BCAP 10240       // per-bucket edge capacity (mean 8192, sigma~90)

__device__ __forceinline__ float bf2f(unsigned short u) {
    return __uint_as_float(((unsigned)u) << 16);
}
__device__ __forceinline__ unsigned short f2bf(float x) {
    unsigned u = __float_as_uint(x);
    unsigned r = (u + 0x7FFFu + ((u >> 16) & 1u)) >> 16;  // RTNE
    return (unsigned short)r;
}

// ---- init: zero bucket counters + pooled --------------------------------
__global__ void init_all(int* __restrict__ bucketCnt, float* __restrict__ pooled) {
    int tid = blockIdx.x * blockDim.x + threadIdx.x;
    int stride = gridDim.x * blockDim.x;
    if (tid < NBUCK) bucketCnt[tid] = 0;
    for (int i = tid; i < G_GRAPHS * HD; i += stride) pooled[i] = 0.f;
}

__global__ void zero256(float* __restrict__ sums) {
    sums[threadIdx.x] = 0.f;
}

// ---- CSR build, phase A: bin edges into 196 coarse dst-buckets ----------
// Writes (src,dst) pairs in ~128B contiguous spans -> full-sector writes.
__global__ __launch_bounds__(256) void bucket_scatter(const int* __restrict__ src,
                                                      const int* __restrict__ dst,
                                                      int* __restrict__ bucketCnt,
                                                      int2* __restrict__ pairs) {
    __shared__ int hist[NBUCK];
    __shared__ int cur[NBUCK];
    int t = threadIdx.x;
    if (t < NBUCK) hist[t] = 0;
    __syncthreads();
    int base = blockIdx.x * 4096;
    int s[16], d[16];
#pragma unroll
    for (int k = 0; k < 16; ++k) {
        int e = base + t + k * 256;
        if (e < N_EDGES) {
            s[k] = src[e];
            d[k] = dst[e];
            atomicAdd(&hist[d[k] >> BSHIFT], 1);
        } else {
            d[k] = -1;
        }
    }
    __syncthreads();
    if (t < NBUCK) {
        int c = hist[t];
        cur[t] = (c > 0) ? atomicAdd(&bucketCnt[t], c) : 0;
    }
    __syncthreads();
#pragma unroll
    for (int k = 0; k < 16; ++k) {
        if (d[k] >= 0) {
            int b = d[k] >> BSHIFT;
            int slot = atomicAdd(&cur[b], 1);
            pairs[(size_t)b * BCAP + slot] = make_int2(s[k], d[k]);
        }
    }
}

// ---- CSR build, phase A2: per-node degree via per-bucket LDS hist -------
__global__ __launch_bounds__(256) void bucket_count(const int* __restrict__ bucketCnt,
                                                    const int2* __restrict__ pairs,
                                                    int* __restrict__ deg) {
    __shared__ int hist[512];
    int b = blockIdx.x, t = threadIdx.x;
    hist[t] = 0;
    hist[t + 256] = 0;
    __syncthreads();
    int cnt = bucketCnt[b];
    int base0 = b << BSHIFT;
    for (int i = t; i < cnt; i += 256) {
        int2 p = pairs[(size_t)b * BCAP + i];
        atomicAdd(&hist[p.y - base0], 1);
    }
    __syncthreads();
    int n0 = base0 + t, n1 = base0 + t + 256;
    if (n0 < N_NODES) deg[n0] = hist[t];
    if (n1 < N_NODES) deg[n1] = hist[t + 256];
}

// ---- prefix scan of deg -> offs ----------------------------------------
__global__ __launch_bounds__(256) void scan1(const int* __restrict__ deg,
                                             int* __restrict__ offs,
                                             int* __restrict__ blksum) {
    __shared__ int bufA[256], bufB[256];
    int t = threadIdx.x;
    int base = blockIdx.x * 1024;
    int idx = base + t * 4;
    int v[4];
#pragma unroll
    for (int i = 0; i < 4; ++i) v[i] = (idx + i < N_NODES) ? deg[idx + i] : 0;
    int s = v[0] + v[1] + v[2] + v[3];
    bufA[t] = s;
    __syncthreads();
    int* a = bufA; int* b = bufB;
    for (int off = 1; off < 256; off <<= 1) {
        int val = a[t];
        if (t >= off) val += a[t - off];
        b[t] = val;
        __syncthreads();
        int* c = a; a = b; b = c;
    }
    int excl = a[t] - s;
#pragma unroll
    for (int i = 0; i < 4; ++i) {
        if (idx + i < N_NODES) offs[idx + i] = excl;
        excl += v[i];
    }
    if (t == 255) blksum[blockIdx.x] = a[255];
}

__global__ void scan2(const int* __restrict__ blksum, int* __restrict__ blkoff) {
    __shared__ int bufA[128], bufB[128];
    int t = threadIdx.x;  // 128 threads
    int v = (t < SCAN_BLOCKS) ? blksum[t] : 0;
    bufA[t] = v;
    __syncthreads();
    int* a = bufA; int* b = bufB;
    for (int off = 1; off < 128; off <<= 1) {
        int val = a[t];
        if (t >= off) val += a[t - off];
        b[t] = val;
        __syncthreads();
        int* c = a; a = b; b = c;
    }
    if (t < SCAN_BLOCKS) blkoff[t] = a[t] - v;
}

__global__ __launch_bounds__(256) void scan3(int* __restrict__ offs,
                                             const int* __restrict__ blkoff) {
    int base = blockIdx.x * 1024;
    int add = blkoff[blockIdx.x];
#pragma unroll
    for (int i = 0; i < 4; ++i) {
        int idx = base + threadIdx.x + i * 256;
        if (idx < N_NODES) offs[idx] += add;
    }
}

// ---- CSR build, phase B: place edges; LDS rank cursors, dense window ----
__global__ __launch_bounds__(256) void bucket_place(const int* __restrict__ bucketCnt,
                                                    const int2* __restrict__ pairs,
                                                    const int* __restrict__ offs,
                                                    int* __restrict__ csr_src) {
    __shared__ int cur[512];
    int b = blockIdx.x, t = threadIdx.x;
    cur[t] = 0;
    cur[t + 256] = 0;
    __syncthreads();
    int cnt = bucketCnt[b];
    int base0 = b << BSHIFT;
    for (int i = t; i < cnt; i += 256) {
        int2 p = pairs[(size_t)b * BCAP + i];
        int r = atomicAdd(&cur[p.y - base0], 1);
        csr_src[offs[p.y] + r] = p.x;
    }
}

// ---- feat_bf16 = bf16(X @ W)  (X:[nrows,128] fp32, W:[128,128]) ---------
__global__ __launch_bounds__(256) void gemm128(const float* __restrict__ X,
                                               const float* __restrict__ W,
                                               unsigned short* __restrict__ Yb,
                                               int nrows) {
    __shared__ float Ws[HD * HD];
    __shared__ float xs[8][HD];
    for (int i = threadIdx.x; i < HD * HD; i += 256) Ws[i] = W[i];
    int c4 = (threadIdx.x & 31) * 4;
    int rs = threadIdx.x >> 5;  // 0..7
    int base = blockIdx.x * 64;
    for (int it = 0; it < 8; ++it) {
        int r0 = base + it * 8;
        __syncthreads();
        {
            int lr = r0 + (threadIdx.x >> 5);
            int lc = (threadIdx.x & 31) * 4;
            if (lr < nrows) *(float4*)&xs[threadIdx.x >> 5][lc] = *(const float4*)&X[lr * HD + lc];
        }
        __syncthreads();
        int r = r0 + rs;
        if (r < nrows) {
            float4 acc = {0.f, 0.f, 0.f, 0.f};
#pragma unroll
            for (int k = 0; k < HD; ++k) {
                float xv = xs[rs][k];
                float4 w = *(float4*)&Ws[k * HD + c4];
                acc.x += xv * w.x; acc.y += xv * w.y;
                acc.z += xv * w.z; acc.w += xv * w.w;
            }
            ushort4 o;
            o.x = f2bf(acc.x); o.y = f2bf(acc.y);
            o.z = f2bf(acc.z); o.w = f2bf(acc.w);
            *(ushort4*)&Yb[r * HD + c4] = o;
        }
    }
}

// ---- el/er from bf16 feat -----------------------------------------------
__global__ void compute_elr(const unsigned short* __restrict__ featb,
                            const float* __restrict__ al,
                            const float* __restrict__ ar, float* __restrict__ el,
                            float* __restrict__ er) {
    int t = blockIdx.x * blockDim.x + threadIdx.x;
    if (t >= N_NODES * H) return;
    int n = t >> 3, h = t & 7;
    const unsigned* fp = (const unsigned*)&featb[n * HD + h * D];
    const float* ap = &al[h * D];
    const float* bp = &ar[h * D];
    float sl = 0.f, sr = 0.f;
#pragma unroll
    for (int i = 0; i < 8; ++i) {
        unsigned u = fp[i];
        float f0 = bf2f((unsigned short)(u & 0xFFFFu));
        float f1 = bf2f((unsigned short)(u >> 16));
        sl += f0 * ap[2 * i] + f1 * ap[2 * i + 1];
        sr += f0 * bp[2 * i] + f1 * bp[2 * i + 1];
    }
    el[t] = sl;
    er[t] = sr;
}

// ---- per-dst-node GAT: SINGLE PASS, normalize by denom at the end -------
__global__ __launch_bounds__(256) void gat_node(const int* __restrict__ offs,
                                                const int* __restrict__ deg,
                                                const int* __restrict__ csr_src,
                                                const float* __restrict__ el,
                                                const float* __restrict__ er,
                                                const unsigned short* __restrict__ featb,
                                                float* __restrict__ gat) {
    int node = blockIdx.x * 4 + (threadIdx.x >> 6);
    if (node >= N_NODES) return;
    int lane = threadIdx.x & 63;
    int h = lane & 7, j = lane >> 3;  // h: head for exp; j: edge slot AND my column head
    int beg = offs[node];
    int end = beg + deg[node];
    float ern = er[node * H + h];
    float dsum = 0.f, accx = 0.f, accy = 0.f;
    for (int p0 = beg; p0 < end; p0 += 8) {
        int cnt = end - p0;
        if (cnt > 8) cnt = 8;
        int sj = 0;
        float ex = 0.f;
        if (j < cnt) {
            sj = csr_src[p0 + j];
            float v = el[sj * H + h] + ern;
            v = v >= 0.f ? v : NEG * v;
            ex = __expf(v);
            dsum += ex;
        }
        if (cnt == 8) {
#pragma unroll
            for (int j2 = 0; j2 < 8; ++j2) {
                int s = __shfl(sj, j2 * 8);
                float wv = __shfl(ex, j2 * 8 + j);
                unsigned pair = *(const unsigned*)&featb[s * HD + lane * 2];
                accx += wv * bf2f((unsigned short)(pair & 0xFFFFu));
                accy += wv * bf2f((unsigned short)(pair >> 16));
            }
        } else {
            for (int j2 = 0; j2 < cnt; ++j2) {
                int s = __shfl(sj, j2 * 8);
                float wv = __shfl(ex, j2 * 8 + j);
                unsigned pair = *(const unsigned*)&featb[s * HD + lane * 2];
                accx += wv * bf2f((unsigned short)(pair & 0xFFFFu));
                accy += wv * bf2f((unsigned short)(pair >> 16));
            }
        }
    }
    dsum += __shfl_xor(dsum, 8);
    dsum += __shfl_xor(dsum, 16);
    dsum += __shfl_xor(dsum, 32);
    float dtot = __shfl(dsum, j);  // lane j has h == j
    float invd = dtot > 0.f ? 1.f / dtot : 0.f;
    float2 o;
    o.x = accx * invd;
    o.y = accy * invd;
    *(float2*)&gat[node * HD + lane * 2] = o;
}

// ---- BN stats: per-column sum and sumsq ---------------------------------
__global__ __launch_bounds__(256) void bn_stats(const float* __restrict__ x,
                                                float* __restrict__ sums, int nrows) {
    int c = threadIdx.x & 127;
    int half = threadIdx.x >> 7;  // 0/1
    float s = 0.f, sq = 0.f;
    for (int r = blockIdx.x * 2 + half; r < nrows; r += gridDim.x * 2) {
        float v = x[r * HD + c];
        s += v;
        sq += v * v;
    }
    __shared__ float ls[256], lq[256];
    ls[threadIdx.x] = s;
    lq[threadIdx.x] = sq;
    __syncthreads();
    if (half == 0) {
        atomicAdd(&sums[c], s + ls[c + 128]);
        atomicAdd(&sums[128 + c], sq + lq[c + 128]);
    }
}

// ---- BN apply + ReLU (+ optional residual) ------------------------------
__global__ void bn_apply(const float* __restrict__ x, const float* __restrict__ sums,
                         const float* __restrict__ g, const float* __restrict__ be,
                         const float* __restrict__ res, float* __restrict__ y, int nrows) {
    int t = blockIdx.x * blockDim.x + threadIdx.x;
    if (t >= nrows * 32) return;
    int n = t >> 5, c4 = (t & 31) * 4;
    float invN = 1.0f / (float)nrows;
    float4 v = *(const float4*)&x[n * HD + c4];
    float4 gv = *(const float4*)&g[c4];
    float4 bv = *(const float4*)&be[c4];
    float4 out;
    float* vp = (float*)&v;
    float* gp = (float*)&gv;
    float* bp = (float*)&bv;
    float* op = (float*)&out;
#pragma unroll
    for (int i = 0; i < 4; ++i) {
        int c = c4 + i;
        float mu = sums[c] * invN;
        float var = sums[128 + c] * invN - mu * mu;
        float rstd = rsqrtf(var + EPS);
        float z = (vp[i] - mu) * rstd * gp[i] + bp[i];
        op[i] = z > 0.f ? z : 0.f;
    }
    if (res) {
        float4 rv = *(const float4*)&res[n * HD + c4];
        out.x += rv.x; out.y += rv.y; out.z += rv.z; out.w += rv.w;
    }
    *(float4*)&y[n * HD + c4] = out;
}

// ---- graph sum-pool: gid is SORTED, run-detect then few atomics ---------
__global__ void pool_sum2(const float* __restrict__ h2, const int* __restrict__ gid,
                          float* __restrict__ pooled) {
    int t = threadIdx.x;  // 128 threads, thread owns column t
    int r0 = blockIdx.x * 256;
    int r1 = r0 + 256 < N_NODES ? r0 + 256 : N_NODES;
    if (r0 >= N_NODES) return;
    float acc = 0.f;
    int cur = gid[r0];
    for (int r = r0; r < r1; ++r) {
        int g = gid[r];
        if (g != cur) {
            atomicAdd(&pooled[cur * HD + t], acc);
            acc = 0.f;
            cur = g;
        }
        acc += h2[r * HD + t];
    }
    atomicAdd(&pooled[cur * HD + t], acc);
}

// ---- masked prediction head ---------------------------------------------
__global__ void pred_kernel(const float* __restrict__ pooled, const float* __restrict__ W,
                            const float* __restrict__ b, const float* __restrict__ mask,
                            float* __restrict__ out) {
    int t = blockIdx.x * blockDim.x + threadIdx.x;
    if (t >= G_GRAPHS * OUT_DIM) return;
    int g = t >> 6, o = t & 63;
    float acc = b[o];
#pragma unroll 4
    for (int c = 0; c < HD; ++c) {
        float m = mask[o * HD + c] > 0.5f ? 1.f : 0.f;
        acc += pooled[g * HD + c] * W[o * HD + c] * m;
    }
    out[t] = acc;
}

extern "C" void kernel_launch(void* const* d_in, const int* in_sizes, int n_in,
                              void* d_out, int out_size, void* d_ws, size_t ws_size,
                              hipStream_t stream) {
    const float* h   = (const float*)d_in[0];
    const int*   src = (const int*)d_in[1];
    const int*   dst = (const int*)d_in[2];
    const int*   gid = (const int*)d_in[3];
    const float* W0  = (const float*)d_in[4];
    const float* al0 = (const float*)d_in[5];
    const float* ar0 = (const float*)d_in[6];
    // d_in[7] = b0 — BN shift-invariance: bias cancels exactly
    const float* g0  = (const float*)d_in[8];
    const float* be0 = (const float*)d_in[9];
    const float* W1  = (const float*)d_in[10];
    const float* al1 = (const float*)d_in[11];
    const float* ar1 = (const float*)d_in[12];
    // d_in[13] = b1 — cancels
    const float* g1  = (const float*)d_in[14];
    const float* be1 = (const float*)d_in[15];
    const float* pW  = (const float*)d_in[16];
    const float* pb  = (const float*)d_in[17];
    const float* msk = (const float*)d_in[18];
    float* out = (float*)d_out;

    // workspace layout (4B units)
    float* gat    = (float*)d_ws;                      // [N,128] fp32; h2 at end
    float* h1     = gat + (size_t)N_NODES * HD;        // [N,128] fp32
    float* el     = h1 + (size_t)N_NODES * HD;         // [N,8]
    float* er     = el + (size_t)N_NODES * H;          // [N,8]
    int*   offs   = (int*)(er + (size_t)N_NODES * H);  // [N]
    int*   deg    = offs + N_NODES;                    // [N]
    int*   csr_src= deg + N_NODES;                     // [E]
    int*   bucketCnt = csr_src + N_EDGES;              // [NBUCK] (rounded 256)
    int*   blksum = bucketCnt + 256;                   // [128]
    int*   blkoff = blksum + 128;                      // [128]
    float* sums   = (float*)(blkoff + 128);            // [256]
    float* pooled = sums + 256;                        // [128,128]
    unsigned short* featb = (unsigned short*)(pooled + G_GRAPHS * HD); // [N,128] bf16
    // pairs aliased over h1 (dead until layer-0 bn_apply, after bucket_place)
    int2*  pairs  = (int2*)h1;                         // [NBUCK*BCAP] = 16 MB < 51 MB

    const int TB = 256;
    dim3 blk(TB);
    int gemm_blocks = (N_NODES + 63) / 64;
    int elr_blocks  = (N_NODES * H + TB - 1) / TB;
    int bsc_blocks  = (N_EDGES + 4095) / 4096;
    int node_blocks = (N_NODES + 3) / 4;
    int app_blocks  = (N_NODES * 32 + TB - 1) / TB;
    int pool_blocks = (N_NODES + 255) / 256;

    // ---------------- CSR build (shared by both layers) ----------------
    init_all<<<64, blk, 0, stream>>>(bucketCnt, pooled);
    bucket_scatter<<<bsc_blocks, blk, 0, stream>>>(src, dst, bucketCnt, pairs);
    bucket_count<<<NBUCK, blk, 0, stream>>>(bucketCnt, pairs, deg);
    scan1<<<SCAN_BLOCKS, blk, 0, stream>>>(deg, offs, blksum);
    scan2<<<1, 128, 0, stream>>>(blksum, blkoff);
    scan3<<<SCAN_BLOCKS, blk, 0, stream>>>(offs, blkoff);
    bucket_place<<<NBUCK, blk, 0, stream>>>(bucketCnt, pairs, offs, csr_src);

    // ---------------- layer 0 ----------------
    gemm128<<<gemm_blocks, blk, 0, stream>>>(h, W0, featb, N_NODES);
    compute_elr<<<elr_blocks, blk, 0, stream>>>(featb, al0, ar0, el, er);
    gat_node<<<node_blocks, blk, 0, stream>>>(offs, deg, csr_src, el, er, featb, gat);
    zero256<<<1, 256, 0, stream>>>(sums);
    bn_stats<<<512, blk, 0, stream>>>(gat, sums, N_NODES);
    bn_apply<<<app_blocks, blk, 0, stream>>>(gat, sums, g0, be0, nullptr, h1, N_NODES);

    // ---------------- layer 1 ----------------
    gemm128<<<gemm_blocks, blk, 0, stream>>>(h1, W1, featb, N_NODES);
    compute_elr<<<elr_blocks, blk, 0, stream>>>(featb, al1, ar1, el, er);
    gat_node<<<node_blocks, blk, 0, stream>>>(offs, deg, csr_src, el, er, featb, gat);
    zero256<<<1, 256, 0, stream>>>(sums);
    bn_stats<<<512, blk, 0, stream>>>(gat, sums, N_NODES);
    // h2 = relu(bn(gat)) + h1, in-place over gat (elementwise-safe)
    bn_apply<<<app_blocks, blk, 0, stream>>>(gat, sums, g1, be1, h1, gat, N_NODES);

    // ---------------- pool + head ----------------
    pool_sum2<<<pool_blocks, 128, 0, stream>>>(gat, gid, pooled);
    pred_kernel<<<(G_GRAPHS * OUT_DIM + TB - 1) / TB, blk, 0, stream>>>(pooled, pW, pb, msk, out);
}

// Round 5
// 613.670 us; speedup vs baseline: 42.4623x; 1.1915x over previous
//
#include <hip/hip_runtime.h>
#include <cstdint>

#define N_NODES 100000
#define N_EDGES 1600000
#define H 8
#define D 16
#define HD 128
#define G_GRAPHS 128
#define OUT_DIM 64
#define EPS 1e-3f
#define NEG 0.2f
#define SCAN_BLOCKS 98   // ceil(100000/1024)
#define NBUCK 196        // ceil(100000/512) dst buckets
#define BSHIFT 9         // 512 nodes per bucket
#define BCAP 10240       // per-bucket edge capacity (mean 8192, sigma~90)
#define MT 64            // GEMM rows per tile
#define APAD 136         // LDS A-tile row stride in halfs (+8 pad: b128 bank-uniform)
#define NTILES 1563      // ceil(100000/64)
#define GEMM_GRID 521    // 521*3 == 1563

typedef __attribute__((ext_vector_type(8))) short bf16x8;
typedef __attribute__((ext_vector_type(4))) float f32x4;
typedef __attribute__((ext_vector_type(8))) unsigned short u16x8;

__device__ __forceinline__ float bf2f(unsigned short u) {
    return __uint_as_float(((unsigned)u) << 16);
}
__device__ __forceinline__ unsigned short f2bf(float x) {
    unsigned u = __float_as_uint(x);
    unsigned r = (u + 0x7FFFu + ((u >> 16) & 1u)) >> 16;  // RTNE
    return (unsigned short)r;
}

// ---- init: zero bucket counters + pooled --------------------------------
__global__ void init_all(int* __restrict__ bucketCnt, float* __restrict__ pooled) {
    int tid = blockIdx.x * blockDim.x + threadIdx.x;
    int stride = gridDim.x * blockDim.x;
    if (tid < NBUCK) bucketCnt[tid] = 0;
    for (int i = tid; i < G_GRAPHS * HD; i += stride) pooled[i] = 0.f;
}

__global__ void zero256(float* __restrict__ sums) {
    sums[threadIdx.x] = 0.f;
}

// ---- W -> bf16, transposed: Wt[n*128+k] = bf16(W[k*128+n]) --------------
__global__ void convert_wt(const float* __restrict__ W0, const float* __restrict__ W1,
                           unsigned short* __restrict__ Wt0, unsigned short* __restrict__ Wt1) {
    int t = blockIdx.x * blockDim.x + threadIdx.x;
    if (t >= HD * HD) return;
    int k = t >> 7, n = t & 127;
    Wt0[n * HD + k] = f2bf(W0[t]);
    Wt1[n * HD + k] = f2bf(W1[t]);
}

// ---- CSR build, phase A: bin edges into 196 coarse dst-buckets ----------
__global__ __launch_bounds__(256) void bucket_scatter(const int* __restrict__ src,
                                                      const int* __restrict__ dst,
                                                      int* __restrict__ bucketCnt,
                                                      int2* __restrict__ pairs) {
    __shared__ int hist[NBUCK];
    __shared__ int cur[NBUCK];
    int t = threadIdx.x;
    if (t < NBUCK) hist[t] = 0;
    __syncthreads();
    int base = blockIdx.x * 4096;
    int s[16], d[16];
#pragma unroll
    for (int k = 0; k < 16; ++k) {
        int e = base + t + k * 256;
        if (e < N_EDGES) {
            s[k] = src[e];
            d[k] = dst[e];
            atomicAdd(&hist[d[k] >> BSHIFT], 1);
        } else {
            d[k] = -1;
        }
    }
    __syncthreads();
    if (t < NBUCK) {
        int c = hist[t];
        cur[t] = (c > 0) ? atomicAdd(&bucketCnt[t], c) : 0;
    }
    __syncthreads();
#pragma unroll
    for (int k = 0; k < 16; ++k) {
        if (d[k] >= 0) {
            int b = d[k] >> BSHIFT;
            int slot = atomicAdd(&cur[b], 1);
            pairs[(size_t)b * BCAP + slot] = make_int2(s[k], d[k]);
        }
    }
}

// ---- CSR build, phase A2: per-node degree via per-bucket LDS hist -------
__global__ __launch_bounds__(256) void bucket_count(const int* __restrict__ bucketCnt,
                                                    const int2* __restrict__ pairs,
                                                    int* __restrict__ deg) {
    __shared__ int hist[512];
    int b = blockIdx.x, t = threadIdx.x;
    hist[t] = 0;
    hist[t + 256] = 0;
    __syncthreads();
    int cnt = bucketCnt[b];
    int base0 = b << BSHIFT;
    for (int i = t; i < cnt; i += 256) {
        int2 p = pairs[(size_t)b * BCAP + i];
        atomicAdd(&hist[p.y - base0], 1);
    }
    __syncthreads();
    int n0 = base0 + t, n1 = base0 + t + 256;
    if (n0 < N_NODES) deg[n0] = hist[t];
    if (n1 < N_NODES) deg[n1] = hist[t + 256];
}

// ---- prefix scan of deg -> offs ----------------------------------------
__global__ __launch_bounds__(256) void scan1(const int* __restrict__ deg,
                                             int* __restrict__ offs,
                                             int* __restrict__ blksum) {
    __shared__ int bufA[256], bufB[256];
    int t = threadIdx.x;
    int base = blockIdx.x * 1024;
    int idx = base + t * 4;
    int v[4];
#pragma unroll
    for (int i = 0; i < 4; ++i) v[i] = (idx + i < N_NODES) ? deg[idx + i] : 0;
    int s = v[0] + v[1] + v[2] + v[3];
    bufA[t] = s;
    __syncthreads();
    int* a = bufA; int* b = bufB;
    for (int off = 1; off < 256; off <<= 1) {
        int val = a[t];
        if (t >= off) val += a[t - off];
        b[t] = val;
        __syncthreads();
        int* c = a; a = b; b = c;
    }
    int excl = a[t] - s;
#pragma unroll
    for (int i = 0; i < 4; ++i) {
        if (idx + i < N_NODES) offs[idx + i] = excl;
        excl += v[i];
    }
    if (t == 255) blksum[blockIdx.x] = a[255];
}

__global__ void scan2(const int* __restrict__ blksum, int* __restrict__ blkoff) {
    __shared__ int bufA[128], bufB[128];
    int t = threadIdx.x;  // 128 threads
    int v = (t < SCAN_BLOCKS) ? blksum[t] : 0;
    bufA[t] = v;
    __syncthreads();
    int* a = bufA; int* b = bufB;
    for (int off = 1; off < 128; off <<= 1) {
        int val = a[t];
        if (t >= off) val += a[t - off];
        b[t] = val;
        __syncthreads();
        int* c = a; a = b; b = c;
    }
    if (t < SCAN_BLOCKS) blkoff[t] = a[t] - v;
}

__global__ __launch_bounds__(256) void scan3(int* __restrict__ offs,
                                             const int* __restrict__ blkoff) {
    int base = blockIdx.x * 1024;
    int add = blkoff[blockIdx.x];
#pragma unroll
    for (int i = 0; i < 4; ++i) {
        int idx = base + threadIdx.x + i * 256;
        if (idx < N_NODES) offs[idx] += add;
    }
}

// ---- CSR build, phase B: place edges; LDS rank cursors, dense window ----
__global__ __launch_bounds__(256) void bucket_place(const int* __restrict__ bucketCnt,
                                                    const int2* __restrict__ pairs,
                                                    const int* __restrict__ offs,
                                                    int* __restrict__ csr_src) {
    __shared__ int cur[512];
    int b = blockIdx.x, t = threadIdx.x;
    cur[t] = 0;
    cur[t + 256] = 0;
    __syncthreads();
    int cnt = bucketCnt[b];
    int base0 = b << BSHIFT;
    for (int i = t; i < cnt; i += 256) {
        int2 p = pairs[(size_t)b * BCAP + i];
        int r = atomicAdd(&cur[p.y - base0], 1);
        csr_src[offs[p.y] + r] = p.x;
    }
}

// ---- MFMA GEMM: featb = bf16(X @ W), X fp32 [nrows,128], Wt bf16 [n][k] --
// B held entirely in registers (32 fragments); A staged via LDS per 64-row
// tile. Per wave-tile: 4 ds_read_b128 + 32 MFMA.
__global__ __launch_bounds__(256, 2) void gemm_mfma(const float* __restrict__ X,
                                                    const unsigned short* __restrict__ Wt,
                                                    unsigned short* __restrict__ Yb,
                                                    int nrows) {
    __shared__ unsigned short As[MT * APAD];  // 17.4 KB
    int tid = threadIdx.x;
    int wave = tid >> 6, lane = tid & 63;
    int qd = lane >> 4, l16 = lane & 15;

    // B fragments: bfr[nt][kb] covers cols nt*16..+16, k kb*32..+32
    bf16x8 bfr[8][4];
#pragma unroll
    for (int nt = 0; nt < 8; ++nt)
#pragma unroll
        for (int kb = 0; kb < 4; ++kb)
            bfr[nt][kb] = *(const bf16x8*)&Wt[(nt * 16 + l16) * HD + kb * 32 + qd * 8];

    int srow = tid >> 2, scol = (tid & 3) * 32;  // staging: 4 threads/row

    for (int t = blockIdx.x; t < NTILES; t += gridDim.x) {
        int rbase = t * MT;
        // ---- stage A tile (fp32 -> bf16) ----
        {
            int gr = rbase + srow;
            u16x8 o[4];
            if (gr < nrows) {
#pragma unroll
                for (int i = 0; i < 4; ++i) {
                    float4 va = *(const float4*)&X[(size_t)gr * HD + scol + i * 8];
                    float4 vb = *(const float4*)&X[(size_t)gr * HD + scol + i * 8 + 4];
                    o[i][0] = f2bf(va.x); o[i][1] = f2bf(va.y);
                    o[i][2] = f2bf(va.z); o[i][3] = f2bf(va.w);
                    o[i][4] = f2bf(vb.x); o[i][5] = f2bf(vb.y);
                    o[i][6] = f2bf(vb.z); o[i][7] = f2bf(vb.w);
                }
            } else {
#pragma unroll
                for (int i = 0; i < 4; ++i) o[i] = (u16x8)0;
            }
#pragma unroll
            for (int i = 0; i < 4; ++i)
                *(u16x8*)&As[srow * APAD + scol + i * 8] = o[i];
        }
        __syncthreads();
        // ---- compute ----
        f32x4 acc[8];
#pragma unroll
        for (int nt = 0; nt < 8; ++nt) acc[nt] = (f32x4){0.f, 0.f, 0.f, 0.f};
        bf16x8 afr[4];
#pragma unroll
        for (int kb = 0; kb < 4; ++kb)
            afr[kb] = *(const bf16x8*)&As[(wave * 16 + l16) * APAD + kb * 32 + qd * 8];
#pragma unroll
        for (int nt = 0; nt < 8; ++nt)
#pragma unroll
            for (int kb = 0; kb < 4; ++kb)
                acc[nt] = __builtin_amdgcn_mfma_f32_16x16x32_bf16(afr[kb], bfr[nt][kb], acc[nt], 0, 0, 0);
        // ---- write out (C/D: col=l16, row=qd*4+reg) ----
        int orow = rbase + wave * 16 + qd * 4;
        if (orow + 3 < nrows) {
#pragma unroll
            for (int nt = 0; nt < 8; ++nt)
#pragma unroll
                for (int r = 0; r < 4; ++r)
                    Yb[(size_t)(orow + r) * HD + nt * 16 + l16] = f2bf(acc[nt][r]);
        } else {
#pragma unroll
            for (int nt = 0; nt < 8; ++nt)
                for (int r = 0; r < 4; ++r)
                    if (orow + r < nrows)
                        Yb[(size_t)(orow + r) * HD + nt * 16 + l16] = f2bf(acc[nt][r]);
        }
        __syncthreads();
    }
}

// ---- el/er from bf16 feat -----------------------------------------------
__global__ void compute_elr(const unsigned short* __restrict__ featb,
                            const float* __restrict__ al,
                            const float* __restrict__ ar, float* __restrict__ el,
                            float* __restrict__ er) {
    int t = blockIdx.x * blockDim.x + threadIdx.x;
    if (t >= N_NODES * H) return;
    int n = t >> 3, h = t & 7;
    const unsigned* fp = (const unsigned*)&featb[n * HD + h * D];
    const float* ap = &al[h * D];
    const float* bp = &ar[h * D];
    float sl = 0.f, sr = 0.f;
#pragma unroll
    for (int i = 0; i < 8; ++i) {
        unsigned u = fp[i];
        float f0 = bf2f((unsigned short)(u & 0xFFFFu));
        float f1 = bf2f((unsigned short)(u >> 16));
        sl += f0 * ap[2 * i] + f1 * ap[2 * i + 1];
        sr += f0 * bp[2 * i] + f1 * bp[2 * i + 1];
    }
    el[t] = sl;
    er[t] = sr;
}

// ---- per-dst-node GAT: SINGLE PASS, normalize by denom at the end -------
__global__ __launch_bounds__(256) void gat_node(const int* __restrict__ offs,
                                                const int* __restrict__ deg,
                                                const int* __restrict__ csr_src,
                                                const float* __restrict__ el,
                                                const float* __restrict__ er,
                                                const unsigned short* __restrict__ featb,
                                                float* __restrict__ gat) {
    int node = blockIdx.x * 4 + (threadIdx.x >> 6);
    if (node >= N_NODES) return;
    int lane = threadIdx.x & 63;
    int h = lane & 7, j = lane >> 3;  // h: head for exp; j: edge slot AND my column head
    int beg = offs[node];
    int end = beg + deg[node];
    float ern = er[node * H + h];
    float dsum = 0.f, accx = 0.f, accy = 0.f;
    for (int p0 = beg; p0 < end; p0 += 8) {
        int cnt = end - p0;
        if (cnt > 8) cnt = 8;
        int sj = 0;
        float ex = 0.f;
        if (j < cnt) {
            sj = csr_src[p0 + j];
            float v = el[sj * H + h] + ern;
            v = v >= 0.f ? v : NEG * v;
            ex = __expf(v);
            dsum += ex;
        }
        if (cnt == 8) {
#pragma unroll
            for (int j2 = 0; j2 < 8; ++j2) {
                int s = __shfl(sj, j2 * 8);
                float wv = __shfl(ex, j2 * 8 + j);
                unsigned pair = *(const unsigned*)&featb[s * HD + lane * 2];
                accx += wv * bf2f((unsigned short)(pair & 0xFFFFu));
                accy += wv * bf2f((unsigned short)(pair >> 16));
            }
        } else {
            for (int j2 = 0; j2 < cnt; ++j2) {
                int s = __shfl(sj, j2 * 8);
                float wv = __shfl(ex, j2 * 8 + j);
                unsigned pair = *(const unsigned*)&featb[s * HD + lane * 2];
                accx += wv * bf2f((unsigned short)(pair & 0xFFFFu));
                accy += wv * bf2f((unsigned short)(pair >> 16));
            }
        }
    }
    dsum += __shfl_xor(dsum, 8);
    dsum += __shfl_xor(dsum, 16);
    dsum += __shfl_xor(dsum, 32);
    float dtot = __shfl(dsum, j);  // lane j has h == j
    float invd = dtot > 0.f ? 1.f / dtot : 0.f;
    float2 o;
    o.x = accx * invd;
    o.y = accy * invd;
    *(float2*)&gat[node * HD + lane * 2] = o;
}

// ---- BN stats: per-column sum and sumsq ---------------------------------
__global__ __launch_bounds__(256) void bn_stats(const float* __restrict__ x,
                                                float* __restrict__ sums, int nrows) {
    int c = threadIdx.x & 127;
    int half = threadIdx.x >> 7;  // 0/1
    float s = 0.f, sq = 0.f;
    for (int r = blockIdx.x * 2 + half; r < nrows; r += gridDim.x * 2) {
        float v = x[r * HD + c];
        s += v;
        sq += v * v;
    }
    __shared__ float ls[256], lq[256];
    ls[threadIdx.x] = s;
    lq[threadIdx.x] = sq;
    __syncthreads();
    if (half == 0) {
        atomicAdd(&sums[c], s + ls[c + 128]);
        atomicAdd(&sums[128 + c], sq + lq[c + 128]);
    }
}

// ---- BN apply + ReLU (+ optional residual) ------------------------------
__global__ void bn_apply(const float* __restrict__ x, const float* __restrict__ sums,
                         const float* __restrict__ g, const float* __restrict__ be,
                         const float* __restrict__ res, float* __restrict__ y, int nrows) {
    int t = blockIdx.x * blockDim.x + threadIdx.x;
    if (t >= nrows * 32) return;
    int n = t >> 5, c4 = (t & 31) * 4;
    float invN = 1.0f / (float)nrows;
    float4 v = *(const float4*)&x[n * HD + c4];
    float4 gv = *(const float4*)&g[c4];
    float4 bv = *(const float4*)&be[c4];
    float4 out;
    float* vp = (float*)&v;
    float* gp = (float*)&gv;
    float* bp = (float*)&bv;
    float* op = (float*)&out;
#pragma unroll
    for (int i = 0; i < 4; ++i) {
        int c = c4 + i;
        float mu = sums[c] * invN;
        float var = sums[128 + c] * invN - mu * mu;
        float rstd = rsqrtf(var + EPS);
        float z = (vp[i] - mu) * rstd * gp[i] + bp[i];
        op[i] = z > 0.f ? z : 0.f;
    }
    if (res) {
        float4 rv = *(const float4*)&res[n * HD + c4];
        out.x += rv.x; out.y += rv.y; out.z += rv.z; out.w += rv.w;
    }
    *(float4*)&y[n * HD + c4] = out;
}

// ---- graph sum-pool: gid is SORTED, run-detect then few atomics ---------
__global__ void pool_sum2(const float* __restrict__ h2, const int* __restrict__ gid,
                          float* __restrict__ pooled) {
    int t = threadIdx.x;  // 128 threads, thread owns column t
    int r0 = blockIdx.x * 256;
    int r1 = r0 + 256 < N_NODES ? r0 + 256 : N_NODES;
    if (r0 >= N_NODES) return;
    float acc = 0.f;
    int cur = gid[r0];
    for (int r = r0; r < r1; ++r) {
        int g = gid[r];
        if (g != cur) {
            atomicAdd(&pooled[cur * HD + t], acc);
            acc = 0.f;
            cur = g;
        }
        acc += h2[r * HD + t];
    }
    atomicAdd(&pooled[cur * HD + t], acc);
}

// ---- masked prediction head ---------------------------------------------
__global__ void pred_kernel(const float* __restrict__ pooled, const float* __restrict__ W,
                            const float* __restrict__ b, const float* __restrict__ mask,
                            float* __restrict__ out) {
    int t = blockIdx.x * blockDim.x + threadIdx.x;
    if (t >= G_GRAPHS * OUT_DIM) return;
    int g = t >> 6, o = t & 63;
    float acc = b[o];
#pragma unroll 4
    for (int c = 0; c < HD; ++c) {
        float m = mask[o * HD + c] > 0.5f ? 1.f : 0.f;
        acc += pooled[g * HD + c] * W[o * HD + c] * m;
    }
    out[t] = acc;
}

extern "C" void kernel_launch(void* const* d_in, const int* in_sizes, int n_in,
                              void* d_out, int out_size, void* d_ws, size_t ws_size,
                              hipStream_t stream) {
    const float* h   = (const float*)d_in[0];
    const int*   src = (const int*)d_in[1];
    const int*   dst = (const int*)d_in[2];
    const int*   gid = (const int*)d_in[3];
    const float* W0  = (const float*)d_in[4];
    const float* al0 = (const float*)d_in[5];
    const float* ar0 = (const float*)d_in[6];
    // d_in[7] = b0 — BN shift-invariance: bias cancels exactly
    const float* g0  = (const float*)d_in[8];
    const float* be0 = (const float*)d_in[9];
    const float* W1  = (const float*)d_in[10];
    const float* al1 = (const float*)d_in[11];
    const float* ar1 = (const float*)d_in[12];
    // d_in[13] = b1 — cancels
    const float* g1  = (const float*)d_in[14];
    const float* be1 = (const float*)d_in[15];
    const float* pW  = (const float*)d_in[16];
    const float* pb  = (const float*)d_in[17];
    const float* msk = (const float*)d_in[18];
    float* out = (float*)d_out;

    // workspace layout (4B units)
    float* gat    = (float*)d_ws;                      // [N,128] fp32; h2 at end
    float* h1     = gat + (size_t)N_NODES * HD;        // [N,128] fp32
    float* el     = h1 + (size_t)N_NODES * HD;         // [N,8]
    float* er     = el + (size_t)N_NODES * H;          // [N,8]
    int*   offs   = (int*)(er + (size_t)N_NODES * H);  // [N]
    int*   deg    = offs + N_NODES;                    // [N]
    int*   csr_src= deg + N_NODES;                     // [E]
    int*   bucketCnt = csr_src + N_EDGES;              // [NBUCK] (rounded 256)
    int*   blksum = bucketCnt + 256;                   // [128]
    int*   blkoff = blksum + 128;                      // [128]
    float* sums   = (float*)(blkoff + 128);            // [256]
    float* pooled = sums + 256;                        // [128,128]
    unsigned short* featb = (unsigned short*)(pooled + G_GRAPHS * HD); // [N,128] bf16
    unsigned short* wt0 = featb + (size_t)N_NODES * HD; // [128,128] bf16, W0^T
    unsigned short* wt1 = wt0 + HD * HD;                // [128,128] bf16, W1^T
    // pairs aliased over h1 (dead until layer-0 bn_apply, after bucket_place)
    int2*  pairs  = (int2*)h1;                         // [NBUCK*BCAP] = 16 MB < 51 MB

    const int TB = 256;
    dim3 blk(TB);
    int elr_blocks  = (N_NODES * H + TB - 1) / TB;
    int bsc_blocks  = (N_EDGES + 4095) / 4096;
    int node_blocks = (N_NODES + 3) / 4;
    int app_blocks  = (N_NODES * 32 + TB - 1) / TB;
    int pool_blocks = (N_NODES + 255) / 256;

    // ---------------- CSR build + weight convert ----------------
    init_all<<<64, blk, 0, stream>>>(bucketCnt, pooled);
    convert_wt<<<64, blk, 0, stream>>>(W0, W1, wt0, wt1);
    bucket_scatter<<<bsc_blocks, blk, 0, stream>>>(src, dst, bucketCnt, pairs);
    bucket_count<<<NBUCK, blk, 0, stream>>>(bucketCnt, pairs, deg);
    scan1<<<SCAN_BLOCKS, blk, 0, stream>>>(deg, offs, blksum);
    scan2<<<1, 128, 0, stream>>>(blksum, blkoff);
    scan3<<<SCAN_BLOCKS, blk, 0, stream>>>(offs, blkoff);
    bucket_place<<<NBUCK, blk, 0, stream>>>(bucketCnt, pairs, offs, csr_src);

    // ---------------- layer 0 ----------------
    gemm_mfma<<<GEMM_GRID, blk, 0, stream>>>(h, wt0, featb, N_NODES);
    compute_elr<<<elr_blocks, blk, 0, stream>>>(featb, al0, ar0, el, er);
    gat_node<<<node_blocks, blk, 0, stream>>>(offs, deg, csr_src, el, er, featb, gat);
    zero256<<<1, 256, 0, stream>>>(sums);
    bn_stats<<<512, blk, 0, stream>>>(gat, sums, N_NODES);
    bn_apply<<<app_blocks, blk, 0, stream>>>(gat, sums, g0, be0, nullptr, h1, N_NODES);

    // ---------------- layer 1 ----------------
    gemm_mfma<<<GEMM_GRID, blk, 0, stream>>>(h1, wt1, featb, N_NODES);
    compute_elr<<<elr_blocks, blk, 0, stream>>>(featb, al1, ar1, el, er);
    gat_node<<<node_blocks, blk, 0, stream>>>(offs, deg, csr_src, el, er, featb, gat);
    zero256<<<1, 256, 0, stream>>>(sums);
    bn_stats<<<512, blk, 0, stream>>>(gat, sums, N_NODES);
    // h2 = relu(bn(gat)) + h1, in-place over gat (elementwise-safe)
    bn_apply<<<app_blocks, blk, 0, stream>>>(gat, sums, g1, be1, h1, gat, N_NODES);

    // ---------------- pool + head ----------------
    pool_sum2<<<pool_blocks, 128, 0, stream>>>(gat, gid, pooled);
    pred_kernel<<<(G_GRAPHS * OUT_DIM + TB - 1) / TB, blk, 0, stream>>>(pooled, pW, pb, msk, out);
}

// Round 6
// 565.133 us; speedup vs baseline: 46.1092x; 1.0859x over previous
//
#include <hip/hip_runtime.h>
#include <cstdint>

#define N_NODES 100000
#define N_EDGES 1600000
#define H 8
#define D 16
#define HD 128
#define G_GRAPHS 128
#define OUT_DIM 64
#define EPS 1e-3f
#define NEG 0.2f
#define SCAN_BLOCKS 98   // ceil(100000/1024)
#define NBUCK 196        // ceil(100000/512) dst buckets
#define BSHIFT 9         // 512 nodes per bucket
#define BCAP 10240       // per-bucket edge capacity (mean 8192, sigma~90)
#define MT 64            // GEMM rows per tile
#define APAD 136         // LDS A-tile row stride in halfs
#define NTILES 1563      // ceil(100000/64)
#define GEMM_GRID 521    // 521*3 == 1563

typedef __attribute__((ext_vector_type(8))) short bf16x8;
typedef __attribute__((ext_vector_type(4))) float f32x4;
typedef __attribute__((ext_vector_type(8))) unsigned short u16x8;

__device__ __forceinline__ float bf2f(unsigned short u) {
    return __uint_as_float(((unsigned)u) << 16);
}
__device__ __forceinline__ unsigned short f2bf(float x) {
    unsigned u = __float_as_uint(x);
    unsigned r = (u + 0x7FFFu + ((u >> 16) & 1u)) >> 16;  // RTNE
    return (unsigned short)r;
}
__device__ __forceinline__ float plo(unsigned q) {  // low bf16 of pair
    return __uint_as_float(q << 16);
}
__device__ __forceinline__ float phi(unsigned q) {  // high bf16 of pair
    return __uint_as_float(q & 0xFFFF0000u);
}
__device__ __forceinline__ unsigned packbf(float a, float b) {
    return (unsigned)f2bf(a) | ((unsigned)f2bf(b) << 16);
}

// ---- init: zero bucket counters + pooled + both sums buffers ------------
__global__ void init_all(int* __restrict__ bucketCnt, float* __restrict__ pooled,
                         float* __restrict__ sums01) {
    int tid = blockIdx.x * blockDim.x + threadIdx.x;
    int stride = gridDim.x * blockDim.x;
    if (tid < NBUCK) bucketCnt[tid] = 0;
    if (tid < 512) sums01[tid] = 0.f;
    for (int i = tid; i < G_GRAPHS * HD; i += stride) pooled[i] = 0.f;
}

// ---- W -> bf16, transposed: Wt[n*128+k] = bf16(W[k*128+n]) --------------
__global__ void convert_wt(const float* __restrict__ W0, const float* __restrict__ W1,
                           unsigned short* __restrict__ Wt0, unsigned short* __restrict__ Wt1) {
    int t = blockIdx.x * blockDim.x + threadIdx.x;
    if (t >= HD * HD) return;
    int k = t >> 7, n = t & 127;
    Wt0[n * HD + k] = f2bf(W0[t]);
    Wt1[n * HD + k] = f2bf(W1[t]);
}

// ---- CSR build, phase A: bin edges into 196 coarse dst-buckets ----------
__global__ __launch_bounds__(256) void bucket_scatter(const int* __restrict__ src,
                                                      const int* __restrict__ dst,
                                                      int* __restrict__ bucketCnt,
                                                      int2* __restrict__ pairs) {
    __shared__ int hist[NBUCK];
    __shared__ int cur[NBUCK];
    int t = threadIdx.x;
    if (t < NBUCK) hist[t] = 0;
    __syncthreads();
    int base = blockIdx.x * 4096;
    int s[16], d[16];
#pragma unroll
    for (int k = 0; k < 16; ++k) {
        int e = base + t + k * 256;
        if (e < N_EDGES) {
            s[k] = src[e];
            d[k] = dst[e];
            atomicAdd(&hist[d[k] >> BSHIFT], 1);
        } else {
            d[k] = -1;
        }
    }
    __syncthreads();
    if (t < NBUCK) {
        int c = hist[t];
        cur[t] = (c > 0) ? atomicAdd(&bucketCnt[t], c) : 0;
    }
    __syncthreads();
#pragma unroll
    for (int k = 0; k < 16; ++k) {
        if (d[k] >= 0) {
            int b = d[k] >> BSHIFT;
            int slot = atomicAdd(&cur[b], 1);
            pairs[(size_t)b * BCAP + slot] = make_int2(s[k], d[k]);
        }
    }
}

// ---- CSR build, phase A2: per-node degree via per-bucket LDS hist -------
__global__ __launch_bounds__(256) void bucket_count(const int* __restrict__ bucketCnt,
                                                    const int2* __restrict__ pairs,
                                                    int* __restrict__ deg) {
    __shared__ int hist[512];
    int b = blockIdx.x, t = threadIdx.x;
    hist[t] = 0;
    hist[t + 256] = 0;
    __syncthreads();
    int cnt = bucketCnt[b];
    int base0 = b << BSHIFT;
    for (int i = t; i < cnt; i += 256) {
        int2 p = pairs[(size_t)b * BCAP + i];
        atomicAdd(&hist[p.y - base0], 1);
    }
    __syncthreads();
    int n0 = base0 + t, n1 = base0 + t + 256;
    if (n0 < N_NODES) deg[n0] = hist[t];
    if (n1 < N_NODES) deg[n1] = hist[t + 256];
}

// ---- prefix scan of deg -> offs ----------------------------------------
__global__ __launch_bounds__(256) void scan1(const int* __restrict__ deg,
                                             int* __restrict__ offs,
                                             int* __restrict__ blksum) {
    __shared__ int bufA[256], bufB[256];
    int t = threadIdx.x;
    int base = blockIdx.x * 1024;
    int idx = base + t * 4;
    int v[4];
#pragma unroll
    for (int i = 0; i < 4; ++i) v[i] = (idx + i < N_NODES) ? deg[idx + i] : 0;
    int s = v[0] + v[1] + v[2] + v[3];
    bufA[t] = s;
    __syncthreads();
    int* a = bufA; int* b = bufB;
    for (int off = 1; off < 256; off <<= 1) {
        int val = a[t];
        if (t >= off) val += a[t - off];
        b[t] = val;
        __syncthreads();
        int* c = a; a = b; b = c;
    }
    int excl = a[t] - s;
#pragma unroll
    for (int i = 0; i < 4; ++i) {
        if (idx + i < N_NODES) offs[idx + i] = excl;
        excl += v[i];
    }
    if (t == 255) blksum[blockIdx.x] = a[255];
}

__global__ void scan2(const int* __restrict__ blksum, int* __restrict__ blkoff) {
    __shared__ int bufA[128], bufB[128];
    int t = threadIdx.x;  // 128 threads
    int v = (t < SCAN_BLOCKS) ? blksum[t] : 0;
    bufA[t] = v;
    __syncthreads();
    int* a = bufA; int* b = bufB;
    for (int off = 1; off < 128; off <<= 1) {
        int val = a[t];
        if (t >= off) val += a[t - off];
        b[t] = val;
        __syncthreads();
        int* c = a; a = b; b = c;
    }
    if (t < SCAN_BLOCKS) blkoff[t] = a[t] - v;
}

__global__ __launch_bounds__(256) void scan3(int* __restrict__ offs,
                                             const int* __restrict__ blkoff) {
    int base = blockIdx.x * 1024;
    int add = blkoff[blockIdx.x];
#pragma unroll
    for (int i = 0; i < 4; ++i) {
        int idx = base + threadIdx.x + i * 256;
        if (idx < N_NODES) offs[idx] += add;
    }
}

// ---- CSR build, phase B: place edges; LDS rank cursors, dense window ----
__global__ __launch_bounds__(256) void bucket_place(const int* __restrict__ bucketCnt,
                                                    const int2* __restrict__ pairs,
                                                    const int* __restrict__ offs,
                                                    int* __restrict__ csr_src) {
    __shared__ int cur[512];
    int b = blockIdx.x, t = threadIdx.x;
    cur[t] = 0;
    cur[t + 256] = 0;
    __syncthreads();
    int cnt = bucketCnt[b];
    int base0 = b << BSHIFT;
    for (int i = t; i < cnt; i += 256) {
        int2 p = pairs[(size_t)b * BCAP + i];
        int r = atomicAdd(&cur[p.y - base0], 1);
        csr_src[offs[p.y] + r] = p.x;
    }
}

// ---- MFMA GEMM: featb = bf16(X @ W); A fp32 or bf16 per template --------
template <bool A_BF16>
__global__ __launch_bounds__(256, 2) void gemm_mfma(const void* __restrict__ Xv,
                                                    const unsigned short* __restrict__ Wt,
                                                    unsigned short* __restrict__ Yb,
                                                    int nrows) {
    __shared__ unsigned short As[MT * APAD];
    int tid = threadIdx.x;
    int wave = tid >> 6, lane = tid & 63;
    int qd = lane >> 4, l16 = lane & 15;

    bf16x8 bfr[8][4];
#pragma unroll
    for (int nt = 0; nt < 8; ++nt)
#pragma unroll
        for (int kb = 0; kb < 4; ++kb)
            bfr[nt][kb] = *(const bf16x8*)&Wt[(nt * 16 + l16) * HD + kb * 32 + qd * 8];

    int srow = tid >> 2, scol = (tid & 3) * 32;  // 4 threads/row, 32 halfs each

    for (int t = blockIdx.x; t < NTILES; t += gridDim.x) {
        int rbase = t * MT;
        {
            int gr = rbase + srow;
            u16x8 o[4];
            if (gr < nrows) {
                if (A_BF16) {
                    const unsigned short* X16 = (const unsigned short*)Xv;
#pragma unroll
                    for (int i = 0; i < 4; ++i)
                        o[i] = *(const u16x8*)&X16[(size_t)gr * HD + scol + i * 8];
                } else {
                    const float* X = (const float*)Xv;
#pragma unroll
                    for (int i = 0; i < 4; ++i) {
                        float4 va = *(const float4*)&X[(size_t)gr * HD + scol + i * 8];
                        float4 vb = *(const float4*)&X[(size_t)gr * HD + scol + i * 8 + 4];
                        o[i][0] = f2bf(va.x); o[i][1] = f2bf(va.y);
                        o[i][2] = f2bf(va.z); o[i][3] = f2bf(va.w);
                        o[i][4] = f2bf(vb.x); o[i][5] = f2bf(vb.y);
                        o[i][6] = f2bf(vb.z); o[i][7] = f2bf(vb.w);
                    }
                }
            } else {
#pragma unroll
                for (int i = 0; i < 4; ++i) o[i] = (u16x8)0;
            }
#pragma unroll
            for (int i = 0; i < 4; ++i)
                *(u16x8*)&As[srow * APAD + scol + i * 8] = o[i];
        }
        __syncthreads();
        f32x4 acc[8];
#pragma unroll
        for (int nt = 0; nt < 8; ++nt) acc[nt] = (f32x4){0.f, 0.f, 0.f, 0.f};
        bf16x8 afr[4];
#pragma unroll
        for (int kb = 0; kb < 4; ++kb)
            afr[kb] = *(const bf16x8*)&As[(wave * 16 + l16) * APAD + kb * 32 + qd * 8];
#pragma unroll
        for (int nt = 0; nt < 8; ++nt)
#pragma unroll
            for (int kb = 0; kb < 4; ++kb)
                acc[nt] = __builtin_amdgcn_mfma_f32_16x16x32_bf16(afr[kb], bfr[nt][kb], acc[nt], 0, 0, 0);
        int orow = rbase + wave * 16 + qd * 4;
        if (orow + 3 < nrows) {
#pragma unroll
            for (int nt = 0; nt < 8; ++nt)
#pragma unroll
                for (int r = 0; r < 4; ++r)
                    Yb[(size_t)(orow + r) * HD + nt * 16 + l16] = f2bf(acc[nt][r]);
        } else {
#pragma unroll
            for (int nt = 0; nt < 8; ++nt)
                for (int r = 0; r < 4; ++r)
                    if (orow + r < nrows)
                        Yb[(size_t)(orow + r) * HD + nt * 16 + l16] = f2bf(acc[nt][r]);
        }
        __syncthreads();
    }
}

// ---- el/er from bf16 feat -----------------------------------------------
__global__ void compute_elr(const unsigned short* __restrict__ featb,
                            const float* __restrict__ al,
                            const float* __restrict__ ar, float* __restrict__ el,
                            float* __restrict__ er) {
    int t = blockIdx.x * blockDim.x + threadIdx.x;
    if (t >= N_NODES * H) return;
    int n = t >> 3, h = t & 7;
    const unsigned* fp = (const unsigned*)&featb[n * HD + h * D];
    const float* ap = &al[h * D];
    const float* bp = &ar[h * D];
    float sl = 0.f, sr = 0.f;
#pragma unroll
    for (int i = 0; i < 8; ++i) {
        unsigned u = fp[i];
        float f0 = plo(u), f1 = phi(u);
        sl += f0 * ap[2 * i] + f1 * ap[2 * i + 1];
        sr += f0 * bp[2 * i] + f1 * bp[2 * i + 1];
    }
    el[t] = sl;
    er[t] = sr;
}

// ---- per-dst-node GAT: serial-edge, no shuffles, per-lane full denom ----
// Wave serves one node; lane owns cols 2*lane,2*lane+1 (head j=lane>>3).
// Each lane walks ALL edges, so its dsum is the complete denominator.
__global__ __launch_bounds__(256) void gat_node(const int* __restrict__ offs,
                                                const int* __restrict__ deg,
                                                const int* __restrict__ csr_src,
                                                const float* __restrict__ el,
                                                const float* __restrict__ er,
                                                const unsigned* __restrict__ featp,
                                                unsigned* __restrict__ gatb) {
    int node = blockIdx.x * 4 + (threadIdx.x >> 6);
    if (node >= N_NODES) return;
    int lane = threadIdx.x & 63;
    int j = lane >> 3;
    int p = offs[node];
    int pend = p + deg[node];
    float ern = er[node * H + j];
    float dsum = 0.f, accx = 0.f, accy = 0.f;
    for (; p + 4 <= pend; p += 4) {
        int s0 = csr_src[p + 0], s1 = csr_src[p + 1];
        int s2 = csr_src[p + 2], s3 = csr_src[p + 3];
        float v0 = el[s0 * H + j] + ern;
        float v1 = el[s1 * H + j] + ern;
        float v2 = el[s2 * H + j] + ern;
        float v3 = el[s3 * H + j] + ern;
        v0 = fmaxf(v0, NEG * v0); v1 = fmaxf(v1, NEG * v1);
        v2 = fmaxf(v2, NEG * v2); v3 = fmaxf(v3, NEG * v3);
        float e0 = __expf(v0), e1 = __expf(v1);
        float e2 = __expf(v2), e3 = __expf(v3);
        unsigned q0 = featp[(size_t)s0 * 64 + lane];
        unsigned q1 = featp[(size_t)s1 * 64 + lane];
        unsigned q2 = featp[(size_t)s2 * 64 + lane];
        unsigned q3 = featp[(size_t)s3 * 64 + lane];
        dsum += (e0 + e1) + (e2 + e3);
        accx += e0 * plo(q0); accy += e0 * phi(q0);
        accx += e1 * plo(q1); accy += e1 * phi(q1);
        accx += e2 * plo(q2); accy += e2 * phi(q2);
        accx += e3 * plo(q3); accy += e3 * phi(q3);
    }
    for (; p < pend; ++p) {
        int s = csr_src[p];
        float v = el[s * H + j] + ern;
        v = fmaxf(v, NEG * v);
        float e = __expf(v);
        unsigned q = featp[(size_t)s * 64 + lane];
        dsum += e;
        accx += e * plo(q);
        accy += e * phi(q);
    }
    float invd = dsum > 0.f ? 1.f / dsum : 0.f;
    gatb[(size_t)node * 64 + lane] = packbf(accx * invd, accy * invd);
}

// ---- BN stats from bf16 input -------------------------------------------
__global__ __launch_bounds__(256) void bn_stats(const unsigned* __restrict__ xb,
                                                float* __restrict__ sums, int nrows) {
    int cp = threadIdx.x & 63;   // col pair
    int rr = threadIdx.x >> 6;   // 0..3
    float s0 = 0.f, q0 = 0.f, s1 = 0.f, q1 = 0.f;
    for (int r = blockIdx.x * 4 + rr; r < nrows; r += gridDim.x * 4) {
        unsigned u = xb[(size_t)r * 64 + cp];
        float a = plo(u), b = phi(u);
        s0 += a; q0 += a * a;
        s1 += b; q1 += b * b;
    }
    __shared__ float red[4][256];
    red[0][threadIdx.x] = s0;
    red[1][threadIdx.x] = q0;
    red[2][threadIdx.x] = s1;
    red[3][threadIdx.x] = q1;
    __syncthreads();
    if (rr == 0) {
        int c0 = cp * 2, c1 = c0 + 1;
        float ts0 = red[0][cp] + red[0][cp + 64] + red[0][cp + 128] + red[0][cp + 192];
        float tq0 = red[1][cp] + red[1][cp + 64] + red[1][cp + 128] + red[1][cp + 192];
        float ts1 = red[2][cp] + red[2][cp + 64] + red[2][cp + 128] + red[2][cp + 192];
        float tq1 = red[3][cp] + red[3][cp + 64] + red[3][cp + 128] + red[3][cp + 192];
        atomicAdd(&sums[c0], ts0);
        atomicAdd(&sums[128 + c0], tq0);
        atomicAdd(&sums[c1], ts1);
        atomicAdd(&sums[128 + c1], tq1);
    }
}

// ---- layer-0: h1b = bf16(relu(bn(gat))) ---------------------------------
__global__ void bn_apply0(const unsigned* __restrict__ gatb, const float* __restrict__ sums,
                          const float* __restrict__ g, const float* __restrict__ be,
                          unsigned* __restrict__ h1b) {
    int t = blockIdx.x * blockDim.x + threadIdx.x;
    if (t >= N_NODES * 64) return;
    int cp = t & 63;
    int c0 = cp * 2, c1 = c0 + 1;
    float invN = 1.0f / (float)N_NODES;
    float mu0 = sums[c0] * invN, mu1 = sums[c1] * invN;
    float rs0 = rsqrtf(sums[128 + c0] * invN - mu0 * mu0 + EPS);
    float rs1 = rsqrtf(sums[128 + c1] * invN - mu1 * mu1 + EPS);
    unsigned u = gatb[t];
    float z0 = (plo(u) - mu0) * rs0 * g[c0] + be[c0];
    float z1 = (phi(u) - mu1) * rs1 * g[c1] + be[c1];
    z0 = z0 > 0.f ? z0 : 0.f;
    z1 = z1 > 0.f ? z1 : 0.f;
    h1b[t] = packbf(z0, z1);
}

// ---- layer-1 epilogue fused: bn + relu + residual + graph sum-pool ------
__global__ __launch_bounds__(256) void bn_pool(const unsigned* __restrict__ gatb,
                                               const float* __restrict__ sums,
                                               const float* __restrict__ g,
                                               const float* __restrict__ be,
                                               const unsigned* __restrict__ h1b,
                                               const int* __restrict__ gid,
                                               float* __restrict__ pooled) {
    int cp = threadIdx.x & 63;
    int rr = threadIdx.x >> 6;
    int c0 = cp * 2, c1 = c0 + 1;
    float invN = 1.0f / (float)N_NODES;
    float mu0 = sums[c0] * invN, mu1 = sums[c1] * invN;
    float rs0 = rsqrtf(sums[128 + c0] * invN - mu0 * mu0 + EPS);
    float rs1 = rsqrtf(sums[128 + c1] * invN - mu1 * mu1 + EPS);
    float ga0 = g[c0], ga1 = g[c1], b0 = be[c0], b1 = be[c1];
    int r0 = blockIdx.x * 512;
    int rend = r0 + 512 < N_NODES ? r0 + 512 : N_NODES;
    int r = r0 + rr;
    if (r >= rend) return;
    float a0 = 0.f, a1 = 0.f;
    int cur = gid[r];
    for (; r < rend; r += 4) {
        int gg = gid[r];
        if (gg != cur) {
            atomicAdd(&pooled[cur * HD + c0], a0);
            atomicAdd(&pooled[cur * HD + c1], a1);
            a0 = a1 = 0.f;
            cur = gg;
        }
        unsigned u = gatb[(size_t)r * 64 + cp];
        float z0 = (plo(u) - mu0) * rs0 * ga0 + b0;
        float z1 = (phi(u) - mu1) * rs1 * ga1 + b1;
        z0 = z0 > 0.f ? z0 : 0.f;
        z1 = z1 > 0.f ? z1 : 0.f;
        unsigned v = h1b[(size_t)r * 64 + cp];
        a0 += z0 + plo(v);
        a1 += z1 + phi(v);
    }
    atomicAdd(&pooled[cur * HD + c0], a0);
    atomicAdd(&pooled[cur * HD + c1], a1);
}

// ---- masked prediction head ---------------------------------------------
__global__ void pred_kernel(const float* __restrict__ pooled, const float* __restrict__ W,
                            const float* __restrict__ b, const float* __restrict__ mask,
                            float* __restrict__ out) {
    int t = blockIdx.x * blockDim.x + threadIdx.x;
    if (t >= G_GRAPHS * OUT_DIM) return;
    int g = t >> 6, o = t & 63;
    float acc = b[o];
#pragma unroll 4
    for (int c = 0; c < HD; ++c) {
        float m = mask[o * HD + c] > 0.5f ? 1.f : 0.f;
        acc += pooled[g * HD + c] * W[o * HD + c] * m;
    }
    out[t] = acc;
}

extern "C" void kernel_launch(void* const* d_in, const int* in_sizes, int n_in,
                              void* d_out, int out_size, void* d_ws, size_t ws_size,
                              hipStream_t stream) {
    const float* h   = (const float*)d_in[0];
    const int*   src = (const int*)d_in[1];
    const int*   dst = (const int*)d_in[2];
    const int*   gid = (const int*)d_in[3];
    const float* W0  = (const float*)d_in[4];
    const float* al0 = (const float*)d_in[5];
    const float* ar0 = (const float*)d_in[6];
    // d_in[7] = b0 — BN shift-invariance: bias cancels exactly
    const float* g0  = (const float*)d_in[8];
    const float* be0 = (const float*)d_in[9];
    const float* W1  = (const float*)d_in[10];
    const float* al1 = (const float*)d_in[11];
    const float* ar1 = (const float*)d_in[12];
    // d_in[13] = b1 — cancels
    const float* g1  = (const float*)d_in[14];
    const float* be1 = (const float*)d_in[15];
    const float* pW  = (const float*)d_in[16];
    const float* pb  = (const float*)d_in[17];
    const float* msk = (const float*)d_in[18];
    float* out = (float*)d_out;

    // workspace layout
    unsigned short* gatb  = (unsigned short*)d_ws;                 // [N,128] bf16
    unsigned short* h1b   = gatb + (size_t)N_NODES * HD;           // [N,128] bf16
    unsigned short* featb = h1b + (size_t)N_NODES * HD;            // [N,128] bf16
    float* el   = (float*)(featb + (size_t)N_NODES * HD);          // [N,8]
    float* er   = el + (size_t)N_NODES * H;                        // [N,8]
    int*   offs = (int*)(er + (size_t)N_NODES * H);                // [N]
    int*   deg  = offs + N_NODES;                                  // [N]
    int*   csr_src = deg + N_NODES;                                // [E]
    int*   bucketCnt = csr_src + N_EDGES;                          // [256]
    int*   blksum = bucketCnt + 256;                               // [128]
    int*   blkoff = blksum + 128;                                  // [128]
    float* sums0  = (float*)(blkoff + 128);                        // [256]
    float* sums1  = sums0 + 256;                                   // [256]
    float* pooled = sums1 + 256;                                   // [128,128]
    unsigned short* wt0 = (unsigned short*)(pooled + G_GRAPHS * HD); // [128,128] bf16
    unsigned short* wt1 = wt0 + HD * HD;                             // [128,128] bf16
    // pairs aliased over h1b (16.1 MB < 25.6 MB; dead before bn_apply0 writes h1b)
    int2*  pairs  = (int2*)h1b;

    const int TB = 256;
    dim3 blk(TB);
    int elr_blocks  = (N_NODES * H + TB - 1) / TB;
    int bsc_blocks  = (N_EDGES + 4095) / 4096;
    int node_blocks = (N_NODES + 3) / 4;
    int ap0_blocks  = (N_NODES * 64 + TB - 1) / TB;
    int bnp_blocks  = (N_NODES + 511) / 512;

    // ---------------- CSR build + weight convert ----------------
    init_all<<<64, blk, 0, stream>>>(bucketCnt, pooled, sums0);
    convert_wt<<<64, blk, 0, stream>>>(W0, W1, wt0, wt1);
    bucket_scatter<<<bsc_blocks, blk, 0, stream>>>(src, dst, bucketCnt, pairs);
    bucket_count<<<NBUCK, blk, 0, stream>>>(bucketCnt, pairs, deg);
    scan1<<<SCAN_BLOCKS, blk, 0, stream>>>(deg, offs, blksum);
    scan2<<<1, 128, 0, stream>>>(blksum, blkoff);
    scan3<<<SCAN_BLOCKS, blk, 0, stream>>>(offs, blkoff);
    bucket_place<<<NBUCK, blk, 0, stream>>>(bucketCnt, pairs, offs, csr_src);

    // ---------------- layer 0 ----------------
    gemm_mfma<false><<<GEMM_GRID, blk, 0, stream>>>(h, wt0, featb, N_NODES);
    compute_elr<<<elr_blocks, blk, 0, stream>>>(featb, al0, ar0, el, er);
    gat_node<<<node_blocks, blk, 0, stream>>>(offs, deg, csr_src, el, er,
                                              (const unsigned*)featb, (unsigned*)gatb);
    bn_stats<<<512, blk, 0, stream>>>((const unsigned*)gatb, sums0, N_NODES);
    bn_apply0<<<ap0_blocks, blk, 0, stream>>>((const unsigned*)gatb, sums0, g0, be0,
                                              (unsigned*)h1b);

    // ---------------- layer 1 ----------------
    gemm_mfma<true><<<GEMM_GRID, blk, 0, stream>>>(h1b, wt1, featb, N_NODES);
    compute_elr<<<elr_blocks, blk, 0, stream>>>(featb, al1, ar1, el, er);
    gat_node<<<node_blocks, blk, 0, stream>>>(offs, deg, csr_src, el, er,
                                              (const unsigned*)featb, (unsigned*)gatb);
    bn_stats<<<512, blk, 0, stream>>>((const unsigned*)gatb, sums1, N_NODES);
    // fused: bn + relu + residual(h1b) + graph sum-pool
    bn_pool<<<bnp_blocks, blk, 0, stream>>>((const unsigned*)gatb, sums1, g1, be1,
                                            (const unsigned*)h1b, gid, pooled);

    // ---------------- head ----------------
    pred_kernel<<<(G_GRAPHS * OUT_DIM + TB - 1) / TB, blk, 0, stream>>>(pooled, pW, pb, msk, out);
}